// Round 1
// baseline (720.292 us; speedup 1.0000x reference)
//
#include <hip/hip_runtime.h>
#include <math.h>

// ---------------------------------------------------------------------------
// BEVHDMapFusionNet: f32 correctness-first pipeline.
// B*T = 8, H=W=32 (HW=1024), F=128, heads=4, head_dim=32, ego E=16.
//
// Workspace layout (floats):
//   OFF_Q  [0        .. 1048576)  Q  [bt][n][128]   (n-major)
//   OFF_K  [1048576  .. 2097152)  K  [bt][n][128]
//   OFF_V  [2097152  .. 3145728)  V  [bt][n][128]
//   OFF_AT [3145728  .. 4194304)  attn_T [bt][c][n] (channel-major)
//   OFF_FU [4194304  .. 5242880)  fused  [bt][c][n]
//   OFF_BF [5242880  .. 6291456)  bev_feat [bt][c][n]
//   OFF_KV [6291456  .. 7864320)  kv [bt][192][n]
//   OFF_P  = OFF_BF: attention partials [bh*4+ks][n][40]  (5242880 floats)
//            (aliases bev_feat+kv, which are dead once projections finish)
// Total ws: 10485760 floats = 41.9 MB.
// ---------------------------------------------------------------------------

#define OFF_Q  0u
#define OFF_K  1048576u
#define OFF_V  2097152u
#define OFF_AT 3145728u
#define OFF_FU 4194304u
#define OFF_BF 5242880u
#define OFF_KV 6291456u
#define OFF_P  5242880u

#define KSPLIT 4
#define KT 64

// ---------------------------------------------------------------------------
// conv3x3 SAME + bias + relu.  x: (8, Cx, 32, 32) channel-major.
// Channels [Cx, Cin) are ego broadcast (constant per bt, zero in SAME halo).
// Each block: one bt, 4 output channels, half the pixels (z*512 .. z*512+511).
// ---------------------------------------------------------------------------
#define CONV_OCB 4
__global__ __launch_bounds__(256) void conv3x3_relu_kernel(
    const float* __restrict__ x, const float* __restrict__ ego,
    const float* __restrict__ w, const float* __restrict__ bias,
    float* __restrict__ y, int Cx, int Cin, int ybt_stride)
{
    __shared__ float tile[18 * 34];
    const int bt  = blockIdx.x;
    const int ocg = blockIdx.y;
    const int z   = blockIdx.z;       // pixel half: rows z*16 .. z*16+15
    const int tid = threadIdx.x;
    const float* xbt = x + (size_t)bt * Cx * 1024;

    float acc[CONV_OCB][2] = {};

    for (int ic = 0; ic < Cin; ++ic) {
        const bool is_ego = (ic >= Cx);
        const float ev = is_ego ? ego[bt * 16 + (ic - Cx)] : 0.f;
        const float* xp = xbt + (size_t)ic * 1024;

        __syncthreads();   // protect tile from previous iteration's readers
        for (int idx = tid; idx < 18 * 34; idx += 256) {
            int ty = idx / 34, tx = idx % 34;
            int gy = z * 16 + ty - 1, gx = tx - 1;
            float v = 0.f;
            if (gy >= 0 && gy < 32 && gx >= 0 && gx < 32)
                v = is_ego ? ev : xp[gy * 32 + gx];
            tile[idx] = v;
        }
        __syncthreads();

        float wr[CONV_OCB][9];
        #pragma unroll
        for (int o = 0; o < CONV_OCB; ++o) {
            const float* wp = w + ((size_t)(ocg * CONV_OCB + o) * Cin + ic) * 9;
            #pragma unroll
            for (int j = 0; j < 9; ++j) wr[o][j] = wp[j];
        }

        #pragma unroll
        for (int p = 0; p < 2; ++p) {
            int l = tid + p * 256;
            int py = l >> 5, px = l & 31;
            #pragma unroll
            for (int ky = 0; ky < 3; ++ky) {
                #pragma unroll
                for (int kx = 0; kx < 3; ++kx) {
                    float v = tile[(py + ky) * 34 + px + kx];
                    #pragma unroll
                    for (int o = 0; o < CONV_OCB; ++o)
                        acc[o][p] += v * wr[o][ky * 3 + kx];
                }
            }
        }
    }

    #pragma unroll
    for (int o = 0; o < CONV_OCB; ++o) {
        int oc = ocg * CONV_OCB + o;
        float bv = bias[oc];
        #pragma unroll
        for (int p = 0; p < 2; ++p) {
            int l = tid + p * 256;
            float v = acc[o][p] + bv;
            y[(size_t)bt * ybt_stride + (size_t)oc * 1024 + z * 512 + l] = fmaxf(v, 0.f);
        }
    }
}

// ---------------------------------------------------------------------------
// Bilinear 2x upsample 16x16 -> 32x32 (jax.image.resize, half-pixel centers;
// out-of-range tap weight renormalizes onto the edge pixel == clamp both taps).
// Writes into kv channels [128,192).
// ---------------------------------------------------------------------------
__global__ __launch_bounds__(256) void resize_front_kernel(
    const float* __restrict__ front, float* __restrict__ kv)
{
    int idx = blockIdx.x * 256 + threadIdx.x;   // (bt*64 + c)*1024 + pix
    int pix = idx & 1023;
    int btc = idx >> 10;                        // bt*64 + c
    int bt  = btc >> 6;
    int c   = btc & 63;
    int oy = pix >> 5, ox = pix & 31;

    float sy = 0.5f * oy - 0.25f, sx = 0.5f * ox - 0.25f;
    int iy0 = (int)floorf(sy); float fy = sy - iy0;
    int ix0 = (int)floorf(sx); float fx = sx - ix0;
    int iy1 = iy0 + 1, ix1 = ix0 + 1;
    iy0 = max(iy0, 0); iy1 = min(iy1, 15);
    ix0 = max(ix0, 0); ix1 = min(ix1, 15);

    const float* fp = front + (size_t)btc * 256;
    float v00 = fp[iy0 * 16 + ix0], v01 = fp[iy0 * 16 + ix1];
    float v10 = fp[iy1 * 16 + ix0], v11 = fp[iy1 * 16 + ix1];
    float v = (1.f - fy) * ((1.f - fx) * v00 + fx * v01)
            +        fy  * ((1.f - fx) * v10 + fx * v11);

    kv[((size_t)bt * 192 + 128 + c) * 1024 + pix] = v;
}

// ---------------------------------------------------------------------------
// Projection: Y[bt][n][o] (n-major) or Y[bt][o][n] (c-major) =
//   sum_c X[bt][c][n] * W[o][c] (+ bias).  8 outputs per thread.
// grid (4 ntiles, 16 ogroups, 8 bt), 256 threads.
// ---------------------------------------------------------------------------
template <int C, bool NMAJOR, bool HAS_BIAS>
__global__ __launch_bounds__(256) void proj_kernel(
    const float* __restrict__ X, const float* __restrict__ W,
    const float* __restrict__ bias, float* __restrict__ Y)
{
    int n  = blockIdx.x * 256 + threadIdx.x;
    int o0 = blockIdx.y * 8;
    int bt = blockIdx.z;
    const float* xp = X + (size_t)bt * C * 1024 + n;

    float acc[8] = {};
    for (int c = 0; c < C; ++c) {
        float xv = xp[(size_t)c << 10];
        #pragma unroll
        for (int j = 0; j < 8; ++j) acc[j] += xv * W[(o0 + j) * C + c];
    }
    if (HAS_BIAS) {
        #pragma unroll
        for (int j = 0; j < 8; ++j) acc[j] += bias[o0 + j];
    }
    if (NMAJOR) {
        float* yp = Y + ((size_t)(bt * 1024) + n) * 128 + o0;
        #pragma unroll
        for (int j = 0; j < 8; ++j) yp[j] = acc[j];
    } else {
        float* yp = Y + (size_t)bt * 128 * 1024 + n;
        #pragma unroll
        for (int j = 0; j < 8; ++j) yp[(size_t)(o0 + j) << 10] = acc[j];
    }
}

// K and V from the same X in one pass (halves kv traffic).
template <int C>
__global__ __launch_bounds__(256) void proj_kv_kernel(
    const float* __restrict__ X, const float* __restrict__ Wk,
    const float* __restrict__ Wv, float* __restrict__ K, float* __restrict__ V)
{
    int n  = blockIdx.x * 256 + threadIdx.x;
    int o0 = blockIdx.y * 8;
    int bt = blockIdx.z;
    const float* xp = X + (size_t)bt * C * 1024 + n;

    float ak[8] = {}, av[8] = {};
    for (int c = 0; c < C; ++c) {
        float xv = xp[(size_t)c << 10];
        #pragma unroll
        for (int j = 0; j < 8; ++j) {
            ak[j] += xv * Wk[(o0 + j) * C + c];
            av[j] += xv * Wv[(o0 + j) * C + c];
        }
    }
    size_t base = ((size_t)(bt * 1024) + n) * 128 + o0;
    #pragma unroll
    for (int j = 0; j < 8; ++j) { K[base + j] = ak[j]; V[base + j] = av[j]; }
}

// ---------------------------------------------------------------------------
// Attention, thread-per-query online softmax, key-split x4.
// grid (8 qtiles, 4 heads, bt*4+ks), 128 threads (1 query each, 256 keys).
// Partial [bh*4+ks][n][40]: [0]=m, [1]=l, [8..39]=acc (16B aligned).
// ---------------------------------------------------------------------------
__global__ __launch_bounds__(128) void attn_kernel(
    const float* __restrict__ Q, const float* __restrict__ K,
    const float* __restrict__ V, float* __restrict__ part)
{
    __shared__ float Kt[KT * 32], Vt[KT * 32];
    const int qt = blockIdx.x, h = blockIdx.y;
    const int bt = blockIdx.z >> 2, ks = blockIdx.z & 3;
    const int tid = threadIdx.x;
    const int n = qt * 128 + tid;

    float q[32];
    const float4* qp4 = (const float4*)(Q + ((size_t)(bt * 1024 + n) * 128 + h * 32));
    #pragma unroll
    for (int j = 0; j < 8; ++j) {
        float4 v4 = qp4[j];
        q[4*j]   = v4.x * 0.1767766953f;   // 1/sqrt(32)
        q[4*j+1] = v4.y * 0.1767766953f;
        q[4*j+2] = v4.z * 0.1767766953f;
        q[4*j+3] = v4.w * 0.1767766953f;
    }

    float m = -INFINITY, l = 0.f;
    float acc[32] = {};

    const float4* K4 = (const float4*)K;
    const float4* V4 = (const float4*)V;
    for (int t = 0; t < 256 / KT; ++t) {
        int k0 = ks * 256 + t * KT;
        // stage K,V tiles (float4, coalesced)
        for (int idx = tid; idx < KT * 8; idx += 128) {
            int kk = idx >> 3, d4 = idx & 7;
            size_t src = (size_t)(bt * 1024 + k0 + kk) * 32 + h * 8 + d4;
            ((float4*)Kt)[idx] = K4[src];
            ((float4*)Vt)[idx] = V4[src];
        }
        __syncthreads();

        for (int kk = 0; kk < KT; ++kk) {
            const float4* kr = (const float4*)&Kt[kk * 32];
            float s = 0.f;
            #pragma unroll
            for (int j = 0; j < 8; ++j) {
                float4 k4 = kr[j];
                s += q[4*j] * k4.x + q[4*j+1] * k4.y + q[4*j+2] * k4.z + q[4*j+3] * k4.w;
            }
            const float4* vr = (const float4*)&Vt[kk * 32];
            if (s <= m) {
                float p = __expf(s - m);
                l += p;
                #pragma unroll
                for (int j = 0; j < 8; ++j) {
                    float4 v4 = vr[j];
                    acc[4*j]   += p * v4.x; acc[4*j+1] += p * v4.y;
                    acc[4*j+2] += p * v4.z; acc[4*j+3] += p * v4.w;
                }
            } else {
                float cr = __expf(m - s);   // exp(-inf)=0 handles first key
                m = s;
                l = l * cr + 1.f;
                #pragma unroll
                for (int j = 0; j < 8; ++j) {
                    float4 v4 = vr[j];
                    acc[4*j]   = acc[4*j]   * cr + v4.x;
                    acc[4*j+1] = acc[4*j+1] * cr + v4.y;
                    acc[4*j+2] = acc[4*j+2] * cr + v4.z;
                    acc[4*j+3] = acc[4*j+3] * cr + v4.w;
                }
            }
        }
        __syncthreads();
    }

    float* pp = part + (size_t)(((bt * 4 + h) * KSPLIT + ks) * 1024 + n) * 40;
    pp[0] = m; pp[1] = l;
    #pragma unroll
    for (int j = 0; j < 32; ++j) pp[8 + j] = acc[j];
}

// Combine key-split partials; write attn_T[bt][h*32+d][n] (channel-major).
__global__ __launch_bounds__(256) void attn_combine_kernel(
    const float* __restrict__ part, float* __restrict__ attnT)
{
    int idx = blockIdx.x * 256 + threadIdx.x;  // bh*1024 + n
    int n = idx & 1023, bh = idx >> 10;
    int bt = bh >> 2, h = bh & 3;

    const float* p[KSPLIT];
    float mv[KSPLIT], lv[KSPLIT];
    float M = -INFINITY;
    #pragma unroll
    for (int ks = 0; ks < KSPLIT; ++ks) {
        p[ks] = part + (size_t)((bh * KSPLIT + ks) * 1024 + n) * 40;
        mv[ks] = p[ks][0]; lv[ks] = p[ks][1];
        M = fmaxf(M, mv[ks]);
    }
    float c[KSPLIT], L = 0.f;
    #pragma unroll
    for (int ks = 0; ks < KSPLIT; ++ks) { c[ks] = __expf(mv[ks] - M); L += lv[ks] * c[ks]; }
    float inv = 1.f / L;

    float* outp = attnT + (size_t)bt * 128 * 1024 + n;
    #pragma unroll
    for (int d = 0; d < 32; ++d) {
        float v = 0.f;
        #pragma unroll
        for (int ks = 0; ks < KSPLIT; ++ks) v += p[ks][8 + d] * c[ks];
        outp[(size_t)(h * 32 + d) << 10] = v * inv;
    }
}

// ---------------------------------------------------------------------------
extern "C" void kernel_launch(void* const* d_in, const int* in_sizes, int n_in,
                              void* d_out, int out_size, void* d_ws, size_t ws_size,
                              hipStream_t stream)
{
    const float* bev   = (const float*)d_in[0];
    const float* hd    = (const float*)d_in[1];
    const float* ego   = (const float*)d_in[2];
    const float* front = (const float*)d_in[3];
    const float* w_bev = (const float*)d_in[4];
    const float* b_bev = (const float*)d_in[5];
    const float* w_hd  = (const float*)d_in[6];
    const float* b_hd  = (const float*)d_in[7];
    const float* wq    = (const float*)d_in[8];
    const float* wk    = (const float*)d_in[9];
    const float* wv    = (const float*)d_in[10];
    const float* wo    = (const float*)d_in[11];
    const float* bo    = (const float*)d_in[12];
    const float* w_out = (const float*)d_in[13];
    const float* b_out = (const float*)d_in[14];
    float* out = (float*)d_out;
    float* ws  = (float*)d_ws;

    float* Qb  = ws + OFF_Q;
    float* Kb  = ws + OFF_K;
    float* Vb  = ws + OFF_V;
    float* ATb = ws + OFF_AT;
    float* FUb = ws + OFF_FU;
    float* BFb = ws + OFF_BF;
    float* KVb = ws + OFF_KV;
    float* Pb  = ws + OFF_P;

    // 1) bev+ego conv -> bev_feat
    conv3x3_relu_kernel<<<dim3(8, 32, 2), 256, 0, stream>>>(
        bev, ego, w_bev, b_bev, BFb, 128, 144, 128 * 1024);
    // 2) hd conv -> kv[0:128]
    conv3x3_relu_kernel<<<dim3(8, 32, 2), 256, 0, stream>>>(
        hd, nullptr, w_hd, b_hd, KVb, 64, 64, 192 * 1024);
    // 3) front resize -> kv[128:192]
    resize_front_kernel<<<2048, 256, 0, stream>>>(front, KVb);
    // 4) Q projection (n-major)
    proj_kernel<128, true, false><<<dim3(4, 16, 8), 256, 0, stream>>>(BFb, wq, nullptr, Qb);
    // 5) K,V projections (n-major)
    proj_kv_kernel<192><<<dim3(4, 16, 8), 256, 0, stream>>>(KVb, wk, wv, Kb, Vb);
    // 6) attention partials (aliases BF/KV region — both dead now)
    attn_kernel<<<dim3(8, 4, 32), 128, 0, stream>>>(Qb, Kb, Vb, Pb);
    // 7) combine -> attn_T (channel-major)
    attn_combine_kernel<<<128, 256, 0, stream>>>(Pb, ATb);
    // 8) output projection + bias -> fused (channel-major)
    proj_kernel<128, false, true><<<dim3(4, 16, 8), 256, 0, stream>>>(ATb, wo, bo, FUb);
    // 9) final conv -> out
    conv3x3_relu_kernel<<<dim3(8, 32, 2), 256, 0, stream>>>(
        FUb, ego, w_out, b_out, out, 128, 144, 128 * 1024);
}

// Round 2
// 710.542 us; speedup vs baseline: 1.0137x; 1.0137x over previous
//
#include <hip/hip_runtime.h>
#include <math.h>

// ---------------------------------------------------------------------------
// BEVHDMapFusionNet: f32 pipeline, round 2.
// Conv rewritten with IC-blocked LDS staging (16 channels per barrier round)
// to fix the measured latency/barrier bottleneck (was 144 barrier rounds with
// 72 FMA each; now 9 rounds with 1152 FMA each).
//
// Workspace layout (floats):
//   OFF_Q  [0        .. 1048576)  Q  [bt][n][128]   (n-major)
//   OFF_K  [1048576  .. 2097152)  K  [bt][n][128]
//   OFF_V  [2097152  .. 3145728)  V  [bt][n][128]
//   OFF_AT [3145728  .. 4194304)  attn_T [bt][c][n] (channel-major)
//   OFF_FU [4194304  .. 5242880)  fused  [bt][c][n]
//   OFF_BF [5242880  .. 6291456)  bev_feat [bt][c][n]
//   OFF_KV [6291456  .. 7864320)  kv [bt][192][n]
//   OFF_P  = OFF_BF: attention partials (alias; bev_feat/kv dead by then)
// ---------------------------------------------------------------------------

#define OFF_Q  0u
#define OFF_K  1048576u
#define OFF_V  2097152u
#define OFF_AT 3145728u
#define OFF_FU 4194304u
#define OFF_BF 5242880u
#define OFF_KV 6291456u
#define OFF_P  5242880u

#define KSPLIT 4
#define KT 64

// ---------------------------------------------------------------------------
// conv3x3 SAME + bias + relu.  x: (8, Cx, 32, 32) channel-major.
// Channels [Cx, Cin) are ego broadcast (constant per bt, zero outside grid).
// Block: one bt, 4 output channels, half the rows (z*16 .. z*16+15).
// IC_BLK input channels staged to LDS per barrier round.
// ---------------------------------------------------------------------------
#define CONV_OCB 4
#define IC_BLK 16
#define TILE_E (18 * 34)   // 612 floats per channel tile (18 rows x 34 cols)

__global__ __launch_bounds__(256) void conv3x3_relu_kernel(
    const float* __restrict__ x, const float* __restrict__ ego,
    const float* __restrict__ w, const float* __restrict__ bias,
    float* __restrict__ y, int Cx, int Cin, int ybt_stride)
{
    __shared__ float tile[IC_BLK][TILE_E];
    const int bt  = blockIdx.x;
    const int ocg = blockIdx.y;
    const int z   = blockIdx.z;       // row half: rows z*16 .. z*16+15
    const int tid = threadIdx.x;
    const float* xbt = x + (size_t)bt * Cx * 1024;

    float acc[CONV_OCB][2] = {};

    const int nicb = Cin / IC_BLK;    // 144->9, 64->4
    for (int icb = 0; icb < nicb; ++icb) {
        const int ic0 = icb * IC_BLK;

        __syncthreads();   // protect tile from previous round's readers
        // stage IC_BLK channel tiles (halo'd 18x34)
        for (int idx = tid; idx < IC_BLK * TILE_E; idx += 256) {
            int c = idx / TILE_E;
            int e = idx - c * TILE_E;
            int ic = ic0 + c;
            int ty = e / 34, tx = e - ty * 34;
            int gy = z * 16 + ty - 1, gx = tx - 1;
            float v = 0.f;
            if (gy >= 0 && gy < 32 && gx >= 0 && gx < 32) {
                v = (ic >= Cx) ? ego[bt * 16 + (ic - Cx)]
                               : xbt[((size_t)ic << 10) + gy * 32 + gx];
            }
            tile[c][e] = v;
        }
        __syncthreads();

        #pragma unroll 4
        for (int cl = 0; cl < IC_BLK; ++cl) {
            const int ic = ic0 + cl;
            float wr[CONV_OCB][9];
            #pragma unroll
            for (int o = 0; o < CONV_OCB; ++o) {
                const float* wp = w + ((size_t)(ocg * CONV_OCB + o) * Cin + ic) * 9;
                #pragma unroll
                for (int j = 0; j < 9; ++j) wr[o][j] = wp[j];
            }
            #pragma unroll
            for (int p = 0; p < 2; ++p) {
                int l = tid + p * 256;
                int py = l >> 5, px = l & 31;
                #pragma unroll
                for (int ky = 0; ky < 3; ++ky) {
                    #pragma unroll
                    for (int kx = 0; kx < 3; ++kx) {
                        float v = tile[cl][(py + ky) * 34 + px + kx];
                        #pragma unroll
                        for (int o = 0; o < CONV_OCB; ++o)
                            acc[o][p] += v * wr[o][ky * 3 + kx];
                    }
                }
            }
        }
    }

    #pragma unroll
    for (int o = 0; o < CONV_OCB; ++o) {
        int oc = ocg * CONV_OCB + o;
        float bv = bias[oc];
        #pragma unroll
        for (int p = 0; p < 2; ++p) {
            int l = tid + p * 256;
            float v = acc[o][p] + bv;
            y[(size_t)bt * ybt_stride + (size_t)oc * 1024 + z * 512 + l] = fmaxf(v, 0.f);
        }
    }
}

// ---------------------------------------------------------------------------
// Bilinear 2x upsample 16x16 -> 32x32 (jax.image.resize half-pixel; edge
// weight renormalization == clamped taps). Writes kv channels [128,192).
// ---------------------------------------------------------------------------
__global__ __launch_bounds__(256) void resize_front_kernel(
    const float* __restrict__ front, float* __restrict__ kv)
{
    int idx = blockIdx.x * 256 + threadIdx.x;   // (bt*64 + c)*1024 + pix
    int pix = idx & 1023;
    int btc = idx >> 10;
    int bt  = btc >> 6;
    int c   = btc & 63;
    int oy = pix >> 5, ox = pix & 31;

    float sy = 0.5f * oy - 0.25f, sx = 0.5f * ox - 0.25f;
    int iy0 = (int)floorf(sy); float fy = sy - iy0;
    int ix0 = (int)floorf(sx); float fx = sx - ix0;
    int iy1 = iy0 + 1, ix1 = ix0 + 1;
    iy0 = max(iy0, 0); iy1 = min(iy1, 15);
    ix0 = max(ix0, 0); ix1 = min(ix1, 15);

    const float* fp = front + (size_t)btc * 256;
    float v00 = fp[iy0 * 16 + ix0], v01 = fp[iy0 * 16 + ix1];
    float v10 = fp[iy1 * 16 + ix0], v11 = fp[iy1 * 16 + ix1];
    float v = (1.f - fy) * ((1.f - fx) * v00 + fx * v01)
            +        fy  * ((1.f - fx) * v10 + fx * v11);

    kv[((size_t)bt * 192 + 128 + c) * 1024 + pix] = v;
}

// ---------------------------------------------------------------------------
// Projection: Y[bt][n][o] (n-major) or Y[bt][o][n] (c-major) =
//   sum_c X[bt][c][n] * W[o][c] (+ bias).  8 outputs per thread.
// ---------------------------------------------------------------------------
template <int C, bool NMAJOR, bool HAS_BIAS>
__global__ __launch_bounds__(256) void proj_kernel(
    const float* __restrict__ X, const float* __restrict__ W,
    const float* __restrict__ bias, float* __restrict__ Y)
{
    int n  = blockIdx.x * 256 + threadIdx.x;
    int o0 = blockIdx.y * 8;
    int bt = blockIdx.z;
    const float* xp = X + (size_t)bt * C * 1024 + n;

    float acc[8] = {};
    for (int c = 0; c < C; ++c) {
        float xv = xp[(size_t)c << 10];
        #pragma unroll
        for (int j = 0; j < 8; ++j) acc[j] += xv * W[(o0 + j) * C + c];
    }
    if (HAS_BIAS) {
        #pragma unroll
        for (int j = 0; j < 8; ++j) acc[j] += bias[o0 + j];
    }
    if (NMAJOR) {
        float* yp = Y + ((size_t)(bt * 1024) + n) * 128 + o0;
        #pragma unroll
        for (int j = 0; j < 8; ++j) yp[j] = acc[j];
    } else {
        float* yp = Y + (size_t)bt * 128 * 1024 + n;
        #pragma unroll
        for (int j = 0; j < 8; ++j) yp[(size_t)(o0 + j) << 10] = acc[j];
    }
}

// K and V from the same X in one pass.
template <int C>
__global__ __launch_bounds__(256) void proj_kv_kernel(
    const float* __restrict__ X, const float* __restrict__ Wk,
    const float* __restrict__ Wv, float* __restrict__ K, float* __restrict__ V)
{
    int n  = blockIdx.x * 256 + threadIdx.x;
    int o0 = blockIdx.y * 8;
    int bt = blockIdx.z;
    const float* xp = X + (size_t)bt * C * 1024 + n;

    float ak[8] = {}, av[8] = {};
    for (int c = 0; c < C; ++c) {
        float xv = xp[(size_t)c << 10];
        #pragma unroll
        for (int j = 0; j < 8; ++j) {
            ak[j] += xv * Wk[(o0 + j) * C + c];
            av[j] += xv * Wv[(o0 + j) * C + c];
        }
    }
    size_t base = ((size_t)(bt * 1024) + n) * 128 + o0;
    #pragma unroll
    for (int j = 0; j < 8; ++j) { K[base + j] = ak[j]; V[base + j] = av[j]; }
}

// ---------------------------------------------------------------------------
// Attention, thread-per-query online softmax, key-split x4.
// grid (8 qtiles, 4 heads, bt*4+ks), 128 threads.
// Partial [bh*4+ks][n][40]: [0]=m, [1]=l, [8..39]=acc.
// ---------------------------------------------------------------------------
__global__ __launch_bounds__(128) void attn_kernel(
    const float* __restrict__ Q, const float* __restrict__ K,
    const float* __restrict__ V, float* __restrict__ part)
{
    __shared__ float Kt[KT * 32], Vt[KT * 32];
    const int qt = blockIdx.x, h = blockIdx.y;
    const int bt = blockIdx.z >> 2, ks = blockIdx.z & 3;
    const int tid = threadIdx.x;
    const int n = qt * 128 + tid;

    float q[32];
    const float4* qp4 = (const float4*)(Q + ((size_t)(bt * 1024 + n) * 128 + h * 32));
    #pragma unroll
    for (int j = 0; j < 8; ++j) {
        float4 v4 = qp4[j];
        q[4*j]   = v4.x * 0.1767766953f;   // 1/sqrt(32)
        q[4*j+1] = v4.y * 0.1767766953f;
        q[4*j+2] = v4.z * 0.1767766953f;
        q[4*j+3] = v4.w * 0.1767766953f;
    }

    float m = -INFINITY, l = 0.f;
    float acc[32] = {};

    const float4* K4 = (const float4*)K;
    const float4* V4 = (const float4*)V;
    for (int t = 0; t < 256 / KT; ++t) {
        int k0 = ks * 256 + t * KT;
        for (int idx = tid; idx < KT * 8; idx += 128) {
            int kk = idx >> 3, d4 = idx & 7;
            size_t src = (size_t)(bt * 1024 + k0 + kk) * 32 + h * 8 + d4;
            ((float4*)Kt)[idx] = K4[src];
            ((float4*)Vt)[idx] = V4[src];
        }
        __syncthreads();

        for (int kk = 0; kk < KT; ++kk) {
            const float4* kr = (const float4*)&Kt[kk * 32];
            float s = 0.f;
            #pragma unroll
            for (int j = 0; j < 8; ++j) {
                float4 k4 = kr[j];
                s += q[4*j] * k4.x + q[4*j+1] * k4.y + q[4*j+2] * k4.z + q[4*j+3] * k4.w;
            }
            const float4* vr = (const float4*)&Vt[kk * 32];
            if (s <= m) {
                float p = __expf(s - m);
                l += p;
                #pragma unroll
                for (int j = 0; j < 8; ++j) {
                    float4 v4 = vr[j];
                    acc[4*j]   += p * v4.x; acc[4*j+1] += p * v4.y;
                    acc[4*j+2] += p * v4.z; acc[4*j+3] += p * v4.w;
                }
            } else {
                float cr = __expf(m - s);   // exp(-inf)=0 handles first key
                m = s;
                l = l * cr + 1.f;
                #pragma unroll
                for (int j = 0; j < 8; ++j) {
                    float4 v4 = vr[j];
                    acc[4*j]   = acc[4*j]   * cr + v4.x;
                    acc[4*j+1] = acc[4*j+1] * cr + v4.y;
                    acc[4*j+2] = acc[4*j+2] * cr + v4.z;
                    acc[4*j+3] = acc[4*j+3] * cr + v4.w;
                }
            }
        }
        __syncthreads();
    }

    float* pp = part + (size_t)(((bt * 4 + h) * KSPLIT + ks) * 1024 + n) * 40;
    pp[0] = m; pp[1] = l;
    #pragma unroll
    for (int j = 0; j < 32; ++j) pp[8 + j] = acc[j];
}

// Combine key-split partials; write attn_T[bt][h*32+d][n] (channel-major).
__global__ __launch_bounds__(256) void attn_combine_kernel(
    const float* __restrict__ part, float* __restrict__ attnT)
{
    int idx = blockIdx.x * 256 + threadIdx.x;  // bh*1024 + n
    int n = idx & 1023, bh = idx >> 10;
    int bt = bh >> 2, h = bh & 3;

    const float* p[KSPLIT];
    float mv[KSPLIT], lv[KSPLIT];
    float M = -INFINITY;
    #pragma unroll
    for (int ks = 0; ks < KSPLIT; ++ks) {
        p[ks] = part + (size_t)((bh * KSPLIT + ks) * 1024 + n) * 40;
        mv[ks] = p[ks][0]; lv[ks] = p[ks][1];
        M = fmaxf(M, mv[ks]);
    }
    float c[KSPLIT], L = 0.f;
    #pragma unroll
    for (int ks = 0; ks < KSPLIT; ++ks) { c[ks] = __expf(mv[ks] - M); L += lv[ks] * c[ks]; }
    float inv = 1.f / L;

    float* outp = attnT + (size_t)bt * 128 * 1024 + n;
    #pragma unroll
    for (int d = 0; d < 32; ++d) {
        float v = 0.f;
        #pragma unroll
        for (int ks = 0; ks < KSPLIT; ++ks) v += p[ks][8 + d] * c[ks];
        outp[(size_t)(h * 32 + d) << 10] = v * inv;
    }
}

// ---------------------------------------------------------------------------
extern "C" void kernel_launch(void* const* d_in, const int* in_sizes, int n_in,
                              void* d_out, int out_size, void* d_ws, size_t ws_size,
                              hipStream_t stream)
{
    const float* bev   = (const float*)d_in[0];
    const float* hd    = (const float*)d_in[1];
    const float* ego   = (const float*)d_in[2];
    const float* front = (const float*)d_in[3];
    const float* w_bev = (const float*)d_in[4];
    const float* b_bev = (const float*)d_in[5];
    const float* w_hd  = (const float*)d_in[6];
    const float* b_hd  = (const float*)d_in[7];
    const float* wq    = (const float*)d_in[8];
    const float* wk    = (const float*)d_in[9];
    const float* wv    = (const float*)d_in[10];
    const float* wo    = (const float*)d_in[11];
    const float* bo    = (const float*)d_in[12];
    const float* w_out = (const float*)d_in[13];
    const float* b_out = (const float*)d_in[14];
    float* out = (float*)d_out;
    float* ws  = (float*)d_ws;

    float* Qb  = ws + OFF_Q;
    float* Kb  = ws + OFF_K;
    float* Vb  = ws + OFF_V;
    float* ATb = ws + OFF_AT;
    float* FUb = ws + OFF_FU;
    float* BFb = ws + OFF_BF;
    float* KVb = ws + OFF_KV;
    float* Pb  = ws + OFF_P;

    // 1) bev+ego conv -> bev_feat
    conv3x3_relu_kernel<<<dim3(8, 32, 2), 256, 0, stream>>>(
        bev, ego, w_bev, b_bev, BFb, 128, 144, 128 * 1024);
    // 2) hd conv -> kv[0:128]
    conv3x3_relu_kernel<<<dim3(8, 32, 2), 256, 0, stream>>>(
        hd, nullptr, w_hd, b_hd, KVb, 64, 64, 192 * 1024);
    // 3) front resize -> kv[128:192]
    resize_front_kernel<<<2048, 256, 0, stream>>>(front, KVb);
    // 4) Q projection (n-major)
    proj_kernel<128, true, false><<<dim3(4, 16, 8), 256, 0, stream>>>(BFb, wq, nullptr, Qb);
    // 5) K,V projections (n-major)
    proj_kv_kernel<192><<<dim3(4, 16, 8), 256, 0, stream>>>(KVb, wk, wv, Kb, Vb);
    // 6) attention partials (aliases BF/KV region — both dead now)
    attn_kernel<<<dim3(8, 4, 32), 128, 0, stream>>>(Qb, Kb, Vb, Pb);
    // 7) combine -> attn_T (channel-major)
    attn_combine_kernel<<<128, 256, 0, stream>>>(Pb, ATb);
    // 8) output projection + bias -> fused (channel-major)
    proj_kernel<128, false, true><<<dim3(4, 16, 8), 256, 0, stream>>>(ATb, wo, bo, FUb);
    // 9) final conv -> out
    conv3x3_relu_kernel<<<dim3(8, 32, 2), 256, 0, stream>>>(
        FUb, ego, w_out, b_out, out, 128, 144, 128 * 1024);
}

// Round 3
// 369.967 us; speedup vs baseline: 1.9469x; 1.9206x over previous
//
#include <hip/hip_runtime.h>
#include <math.h>

// ---------------------------------------------------------------------------
// BEVHDMapFusionNet round 3: convs -> MFMA implicit GEMM (bf16), rest f32.
//
// Workspace (float offsets):
//   OFF_Q   0         Q [bt][n][128]
//   OFF_K   1048576   K
//   OFF_V   2097152   V
//   OFF_AT  3145728   attn_T [bt][c][n]
//   OFF_FU  4194304   fused  [bt][c][n]      (aliased by P after S6)
//   OFF_BF  5242880   bev_feat [bt][c][n]    (dead after Q-proj; P aliases)
//   OFF_KV  6291456   kv [bt][192][n]        (dead after KV-proj; P aliases)
//   OFF_XT1 7864320   xT1 bf16 [8][34][34][128] (dead after conv1; P aliases)
//   OFF_XT2 8456192   xT2 bf16 [8][34][34][64]  (dead after conv2; P aliases)
//   OFF_P   4194304   attn partials [128][1024][36] -> ends 8912896
//   OFF_XT3 8912896   xT3 bf16 [8][34][34][128]
//   OFF_WB1 9504768   Wb1 bf16 [9][128][128]
//   OFF_WB2 9578496   Wb2 bf16 [9][128][64]
//   OFF_WB3 9615360   Wb3 bf16 [9][128][128]
//   OFF_E1  9689088   E1 f32 [8][128][9]  (bias + ego border contribution)
//   OFF_E2  9698304   E2 (bias only)
//   OFF_E3  9707520   E3 -> ends 9716736 floats = 38.9 MB
// ---------------------------------------------------------------------------

#define OFF_Q   0u
#define OFF_K   1048576u
#define OFF_V   2097152u
#define OFF_AT  3145728u
#define OFF_FU  4194304u
#define OFF_BF  5242880u
#define OFF_KV  6291456u
#define OFF_XT1 7864320u
#define OFF_XT2 8456192u
#define OFF_P   4194304u
#define OFF_XT3 8912896u
#define OFF_WB1 9504768u
#define OFF_WB2 9578496u
#define OFF_WB3 9615360u
#define OFF_E1  9689088u
#define OFF_E2  9698304u
#define OFF_E3  9707520u

#define KSPLIT 4
#define KT 64
#define PSTRIDE 36

typedef short s16x8 __attribute__((ext_vector_type(8)));
typedef float f32x4 __attribute__((ext_vector_type(4)));

__device__ __forceinline__ unsigned short f2bf(float f) {
    unsigned u = __float_as_uint(f);
    unsigned r = (u + 0x7fffu + ((u >> 16) & 1u)) >> 16;   // RNE
    return (unsigned short)r;
}

__device__ __forceinline__ void gl_lds16(const void* g, void* l) {
    __builtin_amdgcn_global_load_lds(
        (const __attribute__((address_space(1))) unsigned int*)g,
        (__attribute__((address_space(3))) unsigned int*)l, 16, 0, 0);
}

// ---------------------------------------------------------------------------
// Weight pack: w f32 [oc][Cin][3][3] -> Wb bf16 [tap][oc][C] (C excludes ego).
// Segments: Wb1 (Cin=144,C=128), Wb2 (64,64), Wb3 (144,128).
// ---------------------------------------------------------------------------
__global__ __launch_bounds__(256) void wprep_kernel(
    const float* __restrict__ w_bev, const float* __restrict__ w_hd,
    const float* __restrict__ w_out, unsigned short* __restrict__ Wb1,
    unsigned short* __restrict__ Wb2, unsigned short* __restrict__ Wb3)
{
    int gid = blockIdx.x * 256 + threadIdx.x;   // 0 .. 368639
    const float* w; unsigned short* dst; int C, Cin, idx;
    if (gid < 147456)      { w = w_bev; dst = Wb1; C = 128; Cin = 144; idx = gid; }
    else if (gid < 221184) { w = w_hd;  dst = Wb2; C = 64;  Cin = 64;  idx = gid - 147456; }
    else                   { w = w_out; dst = Wb3; C = 128; Cin = 144; idx = gid - 221184; }
    int tap = idx / (128 * C);
    int rem = idx - tap * 128 * C;
    int oc = rem / C, ic = rem - oc * C;
    dst[idx] = f2bf(w[((size_t)oc * Cin + ic) * 9 + tap]);
}

// ---------------------------------------------------------------------------
// E tables: E[bt][oc][rc*3+cc] = bias[oc] + sum_{ic<16} ego * sum_{valid taps} w_ego.
// which 0: bev (ego), 1: hd (bias only), 2: out (ego).
// ---------------------------------------------------------------------------
__global__ __launch_bounds__(256) void eprep_kernel(
    const float* __restrict__ ego,
    const float* __restrict__ w_bev, const float* __restrict__ b_bev,
    const float* __restrict__ b_hd,
    const float* __restrict__ w_out, const float* __restrict__ b_out,
    float* __restrict__ E1, float* __restrict__ E2, float* __restrict__ E3)
{
    int gid = blockIdx.x * 256 + threadIdx.x;   // 0 .. 27647
    int which = gid / 9216;
    int rem = gid - which * 9216;
    int bt = rem / 1152;
    int r2 = rem - bt * 1152;
    int oc = r2 / 9, cls = r2 - oc * 9;
    int rc = cls / 3, cc = cls - rc * 3;

    if (which == 1) { E2[rem] = b_hd[oc]; return; }
    const float* w = (which == 0) ? w_bev : w_out;
    const float* b = (which == 0) ? b_bev : b_out;
    float* E = (which == 0) ? E1 : E3;

    int kyLo = (rc == 0) ? 1 : 0, kyHi = (rc == 2) ? 1 : 2;
    int kxLo = (cc == 0) ? 1 : 0, kxHi = (cc == 2) ? 1 : 2;
    float s = b[oc];
    for (int j = 0; j < 16; ++j) {
        float ev = ego[bt * 16 + j];
        const float* wp = w + ((size_t)oc * 144 + 128 + j) * 9;
        float t = 0.f;
        for (int ky = kyLo; ky <= kyHi; ++ky)
            for (int kx = kxLo; kx <= kxHi; ++kx)
                t += wp[ky * 3 + kx];
        s += ev * t;
    }
    E[rem] = s;
}

// ---------------------------------------------------------------------------
// xT prep: src f32 [bt][C][1024] -> xT bf16 [bt][34][34][C], borders pre-zeroed.
// Thread: one (bt, pixel, 8-ic chunk): coalesced reads along pixels.
// ---------------------------------------------------------------------------
template <int C>
__global__ __launch_bounds__(256) void xtprep_kernel(
    const float* __restrict__ src, unsigned short* __restrict__ xT)
{
    int gid = blockIdx.x * 256 + threadIdx.x;       // bt*(C/8)*1024 + ch*1024 + p
    int p = gid & 1023;
    int ch = (gid >> 10) % (C / 8);
    int bt = gid / (1024 * (C / 8));
    int py = p >> 5, px = p & 31;

    const float* sp = src + (size_t)bt * C * 1024 + (size_t)(ch * 8) * 1024 + p;
    s16x8 v;
    #pragma unroll
    for (int j = 0; j < 8; ++j) v[j] = (short)f2bf(sp[(size_t)j << 10]);
    *(s16x8*)(xT + ((size_t)(bt * 34 + py + 1) * 34 + px + 1) * C + ch * 8) = v;
}

// ---------------------------------------------------------------------------
// MFMA conv: y[bt][oc][px] = relu( sum_taps sum_ic Wb[tap][oc][ic]*xT[...] + E ).
// Block: 128 threads (2 waves), 128 oc x 64 px (2 image rows). grid (16, 8).
// Per 32-ic round: stage halo tile (4 rows x 34 cols x 32 ic bf16) to LDS via
// global_load_lds (linear dest, inverse-swizzled source), then 9 taps x
// (4 A-frags from L2 + 4 B-frags from LDS -> 16 MFMA).
// ---------------------------------------------------------------------------
template <int C, int ROUNDS>
__global__ __launch_bounds__(128) void conv_mfma_kernel(
    const unsigned short* __restrict__ xT, const unsigned short* __restrict__ Wb,
    const float* __restrict__ E, float* __restrict__ y, int ybt_stride)
{
    __shared__ __align__(16) char ldsb[8704];   // 136 e-positions x 64B
    const int pt = blockIdx.x;                  // px tile: rows pt*2, pt*2+1
    const int bt = blockIdx.y;
    const int tid = threadIdx.x;
    const int wave = tid >> 6, lane = tid & 63;
    const int l15 = lane & 15, g = lane >> 4;
    const int oc0 = wave * 64;

    f32x4 acc[4][4];
    #pragma unroll
    for (int a = 0; a < 4; ++a)
        #pragma unroll
        for (int b = 0; b < 4; ++b) acc[a][b] = (f32x4)0.f;

    const unsigned short* xbt = xT + (size_t)bt * 34 * 34 * C;

    for (int kb = 0; kb < ROUNDS; ++kb) {
        const int ic0 = kb * 32;
        __syncthreads();
        // ---- stage 544 16B chunks ----
        #pragma unroll
        for (int i = 0; i < 5; ++i) {
            int ci = i * 128 + tid;
            if (ci < 544) {
                int e = ci >> 2, s = ci & 3;
                int sw = (e + (e >> 2)) & 3;
                int cch = s ^ sw;
                int ty = e / 34, tx = e - ty * 34;
                const unsigned short* src =
                    xbt + ((size_t)(pt * 2 + ty) * 34 + tx) * C + ic0 + cch * 8;
                gl_lds16(src, &ldsb[(i * 128 + wave * 64) * 16]);
            }
        }
        __syncthreads();

        // ---- 9 taps ----
        #pragma unroll
        for (int tap = 0; tap < 9; ++tap) {
            const int ky = tap / 3, kx = tap - ky * 3;
            s16x8 afrag[4], bfrag[4];
            #pragma unroll
            for (int fm = 0; fm < 4; ++fm) {
                const unsigned short* ap =
                    Wb + ((size_t)(tap * 128 + oc0 + fm * 16 + l15)) * C + ic0 + g * 8;
                afrag[fm] = *(const s16x8*)ap;
            }
            #pragma unroll
            for (int fn = 0; fn < 4; ++fn) {
                int e = ((fn >> 1) + ky) * 34 + ((fn & 1) * 16 + l15 + kx);
                int byte = e * 64 + ((g ^ ((e + (e >> 2)) & 3)) << 4);
                bfrag[fn] = *(const s16x8*)(ldsb + byte);
            }
            #pragma unroll
            for (int fm = 0; fm < 4; ++fm)
                #pragma unroll
                for (int fn = 0; fn < 4; ++fn)
                    acc[fm][fn] = __builtin_amdgcn_mfma_f32_16x16x32_bf16(
                        afrag[fm], bfrag[fn], acc[fm][fn], 0, 0, 0);
        }
    }

    // ---- epilogue: + E(border-class) and relu ----
    #pragma unroll
    for (int fn = 0; fn < 4; ++fn) {
        int r = pt * 2 + (fn >> 1);
        int c = (fn & 1) * 16 + l15;
        int rc = (r == 0) ? 0 : ((r == 31) ? 2 : 1);
        int cc = (c == 0) ? 0 : ((c == 31) ? 2 : 1);
        #pragma unroll
        for (int fm = 0; fm < 4; ++fm) {
            #pragma unroll
            for (int rr = 0; rr < 4; ++rr) {
                int oc = oc0 + fm * 16 + g * 4 + rr;
                float ev = E[(bt * 128 + oc) * 9 + rc * 3 + cc];
                float v = acc[fm][fn][rr] + ev;
                y[(size_t)bt * ybt_stride + ((size_t)oc << 10) + r * 32 + c] = fmaxf(v, 0.f);
            }
        }
    }
}

// ---------------------------------------------------------------------------
// Bilinear 2x upsample 16x16 -> 32x32 into kv channels [128,192).
// ---------------------------------------------------------------------------
__global__ __launch_bounds__(256) void resize_front_kernel(
    const float* __restrict__ front, float* __restrict__ kv)
{
    int idx = blockIdx.x * 256 + threadIdx.x;
    int pix = idx & 1023;
    int btc = idx >> 10;
    int bt  = btc >> 6;
    int oy = pix >> 5, ox = pix & 31;

    float sy = 0.5f * oy - 0.25f, sx = 0.5f * ox - 0.25f;
    int iy0 = (int)floorf(sy); float fy = sy - iy0;
    int ix0 = (int)floorf(sx); float fx = sx - ix0;
    int iy1 = iy0 + 1, ix1 = ix0 + 1;
    iy0 = max(iy0, 0); iy1 = min(iy1, 15);
    ix0 = max(ix0, 0); ix1 = min(ix1, 15);

    const float* fp = front + (size_t)btc * 256;
    float v00 = fp[iy0 * 16 + ix0], v01 = fp[iy0 * 16 + ix1];
    float v10 = fp[iy1 * 16 + ix0], v11 = fp[iy1 * 16 + ix1];
    float v = (1.f - fy) * ((1.f - fx) * v00 + fx * v01)
            +        fy  * ((1.f - fx) * v10 + fx * v11);

    kv[((size_t)bt * 192 + 128 + (btc & 63)) * 1024 + pix] = v;
}

// ---------------------------------------------------------------------------
// Projections (unchanged from round 2).
// ---------------------------------------------------------------------------
template <int C, bool NMAJOR, bool HAS_BIAS>
__global__ __launch_bounds__(256) void proj_kernel(
    const float* __restrict__ X, const float* __restrict__ W,
    const float* __restrict__ bias, float* __restrict__ Y)
{
    int n  = blockIdx.x * 256 + threadIdx.x;
    int o0 = blockIdx.y * 8;
    int bt = blockIdx.z;
    const float* xp = X + (size_t)bt * C * 1024 + n;

    float acc[8] = {};
    for (int c = 0; c < C; ++c) {
        float xv = xp[(size_t)c << 10];
        #pragma unroll
        for (int j = 0; j < 8; ++j) acc[j] += xv * W[(o0 + j) * C + c];
    }
    if (HAS_BIAS) {
        #pragma unroll
        for (int j = 0; j < 8; ++j) acc[j] += bias[o0 + j];
    }
    if (NMAJOR) {
        float* yp = Y + ((size_t)(bt * 1024) + n) * 128 + o0;
        #pragma unroll
        for (int j = 0; j < 8; ++j) yp[j] = acc[j];
    } else {
        float* yp = Y + (size_t)bt * 128 * 1024 + n;
        #pragma unroll
        for (int j = 0; j < 8; ++j) yp[(size_t)(o0 + j) << 10] = acc[j];
    }
}

template <int C>
__global__ __launch_bounds__(256) void proj_kv_kernel(
    const float* __restrict__ X, const float* __restrict__ Wk,
    const float* __restrict__ Wv, float* __restrict__ K, float* __restrict__ V)
{
    int n  = blockIdx.x * 256 + threadIdx.x;
    int o0 = blockIdx.y * 8;
    int bt = blockIdx.z;
    const float* xp = X + (size_t)bt * C * 1024 + n;

    float ak[8] = {}, av[8] = {};
    for (int c = 0; c < C; ++c) {
        float xv = xp[(size_t)c << 10];
        #pragma unroll
        for (int j = 0; j < 8; ++j) {
            ak[j] += xv * Wk[(o0 + j) * C + c];
            av[j] += xv * Wv[(o0 + j) * C + c];
        }
    }
    size_t base = ((size_t)(bt * 1024) + n) * 128 + o0;
    #pragma unroll
    for (int j = 0; j < 8; ++j) { K[base + j] = ak[j]; V[base + j] = av[j]; }
}

// ---------------------------------------------------------------------------
// Attention (thread-per-query online softmax, key-split x4). Partial stride 36.
// ---------------------------------------------------------------------------
__global__ __launch_bounds__(128) void attn_kernel(
    const float* __restrict__ Q, const float* __restrict__ K,
    const float* __restrict__ V, float* __restrict__ part)
{
    __shared__ float Kt[KT * 32], Vt[KT * 32];
    const int qt = blockIdx.x, h = blockIdx.y;
    const int bt = blockIdx.z >> 2, ks = blockIdx.z & 3;
    const int tid = threadIdx.x;
    const int n = qt * 128 + tid;

    float q[32];
    const float4* qp4 = (const float4*)(Q + ((size_t)(bt * 1024 + n) * 128 + h * 32));
    #pragma unroll
    for (int j = 0; j < 8; ++j) {
        float4 v4 = qp4[j];
        q[4*j]   = v4.x * 0.1767766953f;
        q[4*j+1] = v4.y * 0.1767766953f;
        q[4*j+2] = v4.z * 0.1767766953f;
        q[4*j+3] = v4.w * 0.1767766953f;
    }

    float m = -INFINITY, l = 0.f;
    float acc[32] = {};

    const float4* K4 = (const float4*)K;
    const float4* V4 = (const float4*)V;
    for (int t = 0; t < 256 / KT; ++t) {
        int k0 = ks * 256 + t * KT;
        for (int idx = tid; idx < KT * 8; idx += 128) {
            int kk = idx >> 3, d4 = idx & 7;
            size_t src = (size_t)(bt * 1024 + k0 + kk) * 32 + h * 8 + d4;
            ((float4*)Kt)[idx] = K4[src];
            ((float4*)Vt)[idx] = V4[src];
        }
        __syncthreads();

        for (int kk = 0; kk < KT; ++kk) {
            const float4* kr = (const float4*)&Kt[kk * 32];
            float s = 0.f;
            #pragma unroll
            for (int j = 0; j < 8; ++j) {
                float4 k4 = kr[j];
                s += q[4*j] * k4.x + q[4*j+1] * k4.y + q[4*j+2] * k4.z + q[4*j+3] * k4.w;
            }
            const float4* vr = (const float4*)&Vt[kk * 32];
            if (s <= m) {
                float p = __expf(s - m);
                l += p;
                #pragma unroll
                for (int j = 0; j < 8; ++j) {
                    float4 v4 = vr[j];
                    acc[4*j]   += p * v4.x; acc[4*j+1] += p * v4.y;
                    acc[4*j+2] += p * v4.z; acc[4*j+3] += p * v4.w;
                }
            } else {
                float cr = __expf(m - s);
                m = s;
                l = l * cr + 1.f;
                #pragma unroll
                for (int j = 0; j < 8; ++j) {
                    float4 v4 = vr[j];
                    acc[4*j]   = acc[4*j]   * cr + v4.x;
                    acc[4*j+1] = acc[4*j+1] * cr + v4.y;
                    acc[4*j+2] = acc[4*j+2] * cr + v4.z;
                    acc[4*j+3] = acc[4*j+3] * cr + v4.w;
                }
            }
        }
        __syncthreads();
    }

    float* pp = part + (size_t)(((bt * 4 + h) * KSPLIT + ks) * 1024 + n) * PSTRIDE;
    pp[0] = m; pp[1] = l;
    #pragma unroll
    for (int j = 0; j < 32; ++j) pp[4 + j] = acc[j];
}

__global__ __launch_bounds__(256) void attn_combine_kernel(
    const float* __restrict__ part, float* __restrict__ attnT)
{
    int idx = blockIdx.x * 256 + threadIdx.x;
    int n = idx & 1023, bh = idx >> 10;
    int bt = bh >> 2, h = bh & 3;

    const float* p[KSPLIT];
    float mv[KSPLIT], lv[KSPLIT];
    float M = -INFINITY;
    #pragma unroll
    for (int ks = 0; ks < KSPLIT; ++ks) {
        p[ks] = part + (size_t)((bh * KSPLIT + ks) * 1024 + n) * PSTRIDE;
        mv[ks] = p[ks][0]; lv[ks] = p[ks][1];
        M = fmaxf(M, mv[ks]);
    }
    float c[KSPLIT], L = 0.f;
    #pragma unroll
    for (int ks = 0; ks < KSPLIT; ++ks) { c[ks] = __expf(mv[ks] - M); L += lv[ks] * c[ks]; }
    float inv = 1.f / L;

    float* outp = attnT + (size_t)bt * 128 * 1024 + n;
    #pragma unroll
    for (int d = 0; d < 32; ++d) {
        float v = 0.f;
        #pragma unroll
        for (int ks = 0; ks < KSPLIT; ++ks) v += p[ks][4 + d] * c[ks];
        outp[(size_t)(h * 32 + d) << 10] = v * inv;
    }
}

// ---------------------------------------------------------------------------
extern "C" void kernel_launch(void* const* d_in, const int* in_sizes, int n_in,
                              void* d_out, int out_size, void* d_ws, size_t ws_size,
                              hipStream_t stream)
{
    const float* bev   = (const float*)d_in[0];
    const float* hd    = (const float*)d_in[1];
    const float* ego   = (const float*)d_in[2];
    const float* front = (const float*)d_in[3];
    const float* w_bev = (const float*)d_in[4];
    const float* b_bev = (const float*)d_in[5];
    const float* w_hd  = (const float*)d_in[6];
    const float* b_hd  = (const float*)d_in[7];
    const float* wq    = (const float*)d_in[8];
    const float* wk    = (const float*)d_in[9];
    const float* wv    = (const float*)d_in[10];
    const float* wo    = (const float*)d_in[11];
    const float* bo    = (const float*)d_in[12];
    const float* w_out = (const float*)d_in[13];
    const float* b_out = (const float*)d_in[14];
    float* out = (float*)d_out;
    float* ws  = (float*)d_ws;

    float* Qb  = ws + OFF_Q;
    float* Kb  = ws + OFF_K;
    float* Vb  = ws + OFF_V;
    float* ATb = ws + OFF_AT;
    float* FUb = ws + OFF_FU;
    float* BFb = ws + OFF_BF;
    float* KVb = ws + OFF_KV;
    float* Pb  = ws + OFF_P;
    unsigned short* xT1 = (unsigned short*)(ws + OFF_XT1);
    unsigned short* xT2 = (unsigned short*)(ws + OFF_XT2);
    unsigned short* xT3 = (unsigned short*)(ws + OFF_XT3);
    unsigned short* Wb1 = (unsigned short*)(ws + OFF_WB1);
    unsigned short* Wb2 = (unsigned short*)(ws + OFF_WB2);
    unsigned short* Wb3 = (unsigned short*)(ws + OFF_WB3);
    float* E1 = ws + OFF_E1;
    float* E2 = ws + OFF_E2;
    float* E3 = ws + OFF_E3;

    // S0: zero xT border regions (covers xT1,xT2,gap,xT3; P overlap is later-written)
    hipMemsetAsync(ws + OFF_XT1, 0, (size_t)(9504768u - OFF_XT1) * 4, stream);

    // S1: prep
    wprep_kernel<<<1440, 256, 0, stream>>>(w_bev, w_hd, w_out, Wb1, Wb2, Wb3);
    eprep_kernel<<<108, 256, 0, stream>>>(ego, w_bev, b_bev, b_hd, w_out, b_out, E1, E2, E3);
    xtprep_kernel<128><<<512, 256, 0, stream>>>(bev, xT1);
    xtprep_kernel<64><<<256, 256, 0, stream>>>(hd, xT2);

    // S2: convs 1,2
    conv_mfma_kernel<128, 4><<<dim3(16, 8), 128, 0, stream>>>(xT1, Wb1, E1, BFb, 128 * 1024);
    conv_mfma_kernel<64, 2><<<dim3(16, 8), 128, 0, stream>>>(xT2, Wb2, E2, KVb, 192 * 1024);

    // S3: resize
    resize_front_kernel<<<2048, 256, 0, stream>>>(front, KVb);

    // S4: projections
    proj_kernel<128, true, false><<<dim3(4, 16, 8), 256, 0, stream>>>(BFb, wq, nullptr, Qb);
    proj_kv_kernel<192><<<dim3(4, 16, 8), 256, 0, stream>>>(KVb, wk, wv, Kb, Vb);

    // S5: attention partials
    attn_kernel<<<dim3(8, 4, 32), 128, 0, stream>>>(Qb, Kb, Vb, Pb);
    // S6: combine
    attn_combine_kernel<<<128, 256, 0, stream>>>(Pb, ATb);
    // S7: output projection
    proj_kernel<128, false, true><<<dim3(4, 16, 8), 256, 0, stream>>>(ATb, wo, bo, FUb);
    // S8: fused -> xT3
    xtprep_kernel<128><<<512, 256, 0, stream>>>(FUb, xT3);
    // S9: final conv
    conv_mfma_kernel<128, 4><<<dim3(16, 8), 128, 0, stream>>>(xT3, Wb3, E3, out, 128 * 1024);
}

// Round 4
// 276.420 us; speedup vs baseline: 2.6058x; 1.3384x over previous
//
#include <hip/hip_runtime.h>
#include <math.h>

// ---------------------------------------------------------------------------
// BEVHDMapFusionNet round 4: convs MFMA (round 3) + attention MFMA (new).
//
// Workspace (float offsets):
//   OFF_AT  0        attn_T f32 [8][128][1024]        -> 1048576
//   OFF_FU  1048576  fused  f32 [8][128][1024]        -> 2097152
//   OFF_BF  2097152  bev_feat f32 [8][128][1024]      -> 3145728
//   OFF_KV  3145728  kv f32 [8][192][1024]            -> 4718592
//   OFF_QBF 4718592  Qbf bf16 [8][1024][128] (scaled) -> 5242880
//   OFF_KBF 5242880  Kbf bf16 [8][1024][128]          -> 5767168
//   OFF_VTB 5767168  VTbf bf16 [32][32][1024]         -> 6291456
//   OFF_XT1 6291456  xT1 bf16 [8][34][34][128]        -> 6883328
//   OFF_XT2 6883328  xT2 bf16 [8][34][34][64]         -> 7179264
//   OFF_XT3 7179264  xT3 bf16 [8][34][34][128]        -> 7771136
//   OFF_WB1 7771136  Wb1 bf16 [9][128][128]           -> 7844864
//   OFF_WB2 7844864  Wb2 bf16 [9][128][64]            -> 7881728
//   OFF_WB3 7881728  Wb3 bf16 [9][128][128]           -> 7955456
//   OFF_E1  7955456  E1 f32 [8][128][9]               -> 7964672
//   OFF_E2  7964672  E2                               -> 7973888
//   OFF_E3  7973888  E3                               -> 7983104  (31.9 MB)
// ---------------------------------------------------------------------------

#define OFF_AT  0u
#define OFF_FU  1048576u
#define OFF_BF  2097152u
#define OFF_KV  3145728u
#define OFF_QBF 4718592u
#define OFF_KBF 5242880u
#define OFF_VTB 5767168u
#define OFF_XT1 6291456u
#define OFF_XT2 6883328u
#define OFF_XT3 7179264u
#define OFF_WB1 7771136u
#define OFF_WB2 7844864u
#define OFF_WB3 7881728u
#define OFF_E1  7955456u
#define OFF_E2  7964672u
#define OFF_E3  7973888u

typedef short s16x8 __attribute__((ext_vector_type(8)));
typedef float f32x4 __attribute__((ext_vector_type(4)));

__device__ __forceinline__ unsigned short f2bf(float f) {
    unsigned u = __float_as_uint(f);
    unsigned r = (u + 0x7fffu + ((u >> 16) & 1u)) >> 16;   // RNE
    return (unsigned short)r;
}

__device__ __forceinline__ void gl_lds16(const void* g, void* l) {
    __builtin_amdgcn_global_load_lds(
        (const __attribute__((address_space(1))) unsigned int*)g,
        (__attribute__((address_space(3))) unsigned int*)l, 16, 0, 0);
}

// ---------------------------------------------------------------------------
// Weight pack: w f32 [oc][Cin][3][3] -> Wb bf16 [tap][oc][C] (C excludes ego).
// ---------------------------------------------------------------------------
__global__ __launch_bounds__(256) void wprep_kernel(
    const float* __restrict__ w_bev, const float* __restrict__ w_hd,
    const float* __restrict__ w_out, unsigned short* __restrict__ Wb1,
    unsigned short* __restrict__ Wb2, unsigned short* __restrict__ Wb3)
{
    int gid = blockIdx.x * 256 + threadIdx.x;   // 0 .. 368639
    const float* w; unsigned short* dst; int C, Cin, idx;
    if (gid < 147456)      { w = w_bev; dst = Wb1; C = 128; Cin = 144; idx = gid; }
    else if (gid < 221184) { w = w_hd;  dst = Wb2; C = 64;  Cin = 64;  idx = gid - 147456; }
    else                   { w = w_out; dst = Wb3; C = 128; Cin = 144; idx = gid - 221184; }
    int tap = idx / (128 * C);
    int rem = idx - tap * 128 * C;
    int oc = rem / C, ic = rem - oc * C;
    dst[idx] = f2bf(w[((size_t)oc * Cin + ic) * 9 + tap]);
}

// ---------------------------------------------------------------------------
// E tables: bias + ego border-class contribution.
// ---------------------------------------------------------------------------
__global__ __launch_bounds__(256) void eprep_kernel(
    const float* __restrict__ ego,
    const float* __restrict__ w_bev, const float* __restrict__ b_bev,
    const float* __restrict__ b_hd,
    const float* __restrict__ w_out, const float* __restrict__ b_out,
    float* __restrict__ E1, float* __restrict__ E2, float* __restrict__ E3)
{
    int gid = blockIdx.x * 256 + threadIdx.x;   // 0 .. 27647
    int which = gid / 9216;
    int rem = gid - which * 9216;
    int bt = rem / 1152;
    int r2 = rem - bt * 1152;
    int oc = r2 / 9, cls = r2 - oc * 9;
    int rc = cls / 3, cc = cls - rc * 3;

    if (which == 1) { E2[rem] = b_hd[oc]; return; }
    const float* w = (which == 0) ? w_bev : w_out;
    const float* b = (which == 0) ? b_bev : b_out;
    float* E = (which == 0) ? E1 : E3;

    int kyLo = (rc == 0) ? 1 : 0, kyHi = (rc == 2) ? 1 : 2;
    int kxLo = (cc == 0) ? 1 : 0, kxHi = (cc == 2) ? 1 : 2;
    float s = b[oc];
    for (int j = 0; j < 16; ++j) {
        float ev = ego[bt * 16 + j];
        const float* wp = w + ((size_t)oc * 144 + 128 + j) * 9;
        float t = 0.f;
        for (int ky = kyLo; ky <= kyHi; ++ky)
            for (int kx = kxLo; kx <= kxHi; ++kx)
                t += wp[ky * 3 + kx];
        s += ev * t;
    }
    E[rem] = s;
}

// ---------------------------------------------------------------------------
// xT prep: src f32 [bt][C][1024] -> xT bf16 [bt][34][34][C], borders pre-zeroed.
// ---------------------------------------------------------------------------
template <int C>
__global__ __launch_bounds__(256) void xtprep_kernel(
    const float* __restrict__ src, unsigned short* __restrict__ xT)
{
    int gid = blockIdx.x * 256 + threadIdx.x;
    int p = gid & 1023;
    int ch = (gid >> 10) % (C / 8);
    int bt = gid / (1024 * (C / 8));
    int py = p >> 5, px = p & 31;

    const float* sp = src + (size_t)bt * C * 1024 + (size_t)(ch * 8) * 1024 + p;
    s16x8 v;
    #pragma unroll
    for (int j = 0; j < 8; ++j) v[j] = (short)f2bf(sp[(size_t)j << 10]);
    *(s16x8*)(xT + ((size_t)(bt * 34 + py + 1) * 34 + px + 1) * C + ch * 8) = v;
}

// ---------------------------------------------------------------------------
// MFMA conv (unchanged from round 3).
// ---------------------------------------------------------------------------
template <int C, int ROUNDS>
__global__ __launch_bounds__(128) void conv_mfma_kernel(
    const unsigned short* __restrict__ xT, const unsigned short* __restrict__ Wb,
    const float* __restrict__ E, float* __restrict__ y, int ybt_stride)
{
    __shared__ __align__(16) char ldsb[8704];
    const int pt = blockIdx.x;
    const int bt = blockIdx.y;
    const int tid = threadIdx.x;
    const int wave = tid >> 6, lane = tid & 63;
    const int l15 = lane & 15, g = lane >> 4;
    const int oc0 = wave * 64;

    f32x4 acc[4][4];
    #pragma unroll
    for (int a = 0; a < 4; ++a)
        #pragma unroll
        for (int b = 0; b < 4; ++b) acc[a][b] = (f32x4)0.f;

    const unsigned short* xbt = xT + (size_t)bt * 34 * 34 * C;

    for (int kb = 0; kb < ROUNDS; ++kb) {
        const int ic0 = kb * 32;
        __syncthreads();
        #pragma unroll
        for (int i = 0; i < 5; ++i) {
            int ci = i * 128 + tid;
            if (ci < 544) {
                int e = ci >> 2, s = ci & 3;
                int sw = (e + (e >> 2)) & 3;
                int cch = s ^ sw;
                int ty = e / 34, tx = e - ty * 34;
                const unsigned short* src =
                    xbt + ((size_t)(pt * 2 + ty) * 34 + tx) * C + ic0 + cch * 8;
                gl_lds16(src, &ldsb[(i * 128 + wave * 64) * 16]);
            }
        }
        __syncthreads();

        #pragma unroll
        for (int tap = 0; tap < 9; ++tap) {
            const int ky = tap / 3, kx = tap - ky * 3;
            s16x8 afrag[4], bfrag[4];
            #pragma unroll
            for (int fm = 0; fm < 4; ++fm) {
                const unsigned short* ap =
                    Wb + ((size_t)(tap * 128 + oc0 + fm * 16 + l15)) * C + ic0 + g * 8;
                afrag[fm] = *(const s16x8*)ap;
            }
            #pragma unroll
            for (int fn = 0; fn < 4; ++fn) {
                int e = ((fn >> 1) + ky) * 34 + ((fn & 1) * 16 + l15 + kx);
                int byte = e * 64 + ((g ^ ((e + (e >> 2)) & 3)) << 4);
                bfrag[fn] = *(const s16x8*)(ldsb + byte);
            }
            #pragma unroll
            for (int fm = 0; fm < 4; ++fm)
                #pragma unroll
                for (int fn = 0; fn < 4; ++fn)
                    acc[fm][fn] = __builtin_amdgcn_mfma_f32_16x16x32_bf16(
                        afrag[fm], bfrag[fn], acc[fm][fn], 0, 0, 0);
        }
    }

    #pragma unroll
    for (int fn = 0; fn < 4; ++fn) {
        int r = pt * 2 + (fn >> 1);
        int c = (fn & 1) * 16 + l15;
        int rc = (r == 0) ? 0 : ((r == 31) ? 2 : 1);
        int cc = (c == 0) ? 0 : ((c == 31) ? 2 : 1);
        #pragma unroll
        for (int fm = 0; fm < 4; ++fm) {
            #pragma unroll
            for (int rr = 0; rr < 4; ++rr) {
                int oc = oc0 + fm * 16 + g * 4 + rr;
                float ev = E[(bt * 128 + oc) * 9 + rc * 3 + cc];
                float v = acc[fm][fn][rr] + ev;
                y[(size_t)bt * ybt_stride + ((size_t)oc << 10) + r * 32 + c] = fmaxf(v, 0.f);
            }
        }
    }
}

// ---------------------------------------------------------------------------
// Bilinear 2x upsample into kv channels [128,192).
// ---------------------------------------------------------------------------
__global__ __launch_bounds__(256) void resize_front_kernel(
    const float* __restrict__ front, float* __restrict__ kv)
{
    int idx = blockIdx.x * 256 + threadIdx.x;
    int pix = idx & 1023;
    int btc = idx >> 10;
    int bt  = btc >> 6;
    int oy = pix >> 5, ox = pix & 31;

    float sy = 0.5f * oy - 0.25f, sx = 0.5f * ox - 0.25f;
    int iy0 = (int)floorf(sy); float fy = sy - iy0;
    int ix0 = (int)floorf(sx); float fx = sx - ix0;
    int iy1 = iy0 + 1, ix1 = ix0 + 1;
    iy0 = max(iy0, 0); iy1 = min(iy1, 15);
    ix0 = max(ix0, 0); ix1 = min(ix1, 15);

    const float* fp = front + (size_t)btc * 256;
    float v00 = fp[iy0 * 16 + ix0], v01 = fp[iy0 * 16 + ix1];
    float v10 = fp[iy1 * 16 + ix0], v11 = fp[iy1 * 16 + ix1];
    float v = (1.f - fy) * ((1.f - fx) * v00 + fx * v01)
            +        fy  * ((1.f - fx) * v10 + fx * v11);

    kv[((size_t)bt * 192 + 128 + (btc & 63)) * 1024 + pix] = v;
}

// ---------------------------------------------------------------------------
// Q projection: X f32 c-major -> Qbf bf16 n-major, pre-scaled by 1/sqrt(32).
// ---------------------------------------------------------------------------
__global__ __launch_bounds__(256) void proj_q_kernel(
    const float* __restrict__ X, const float* __restrict__ W,
    unsigned short* __restrict__ Qbf)
{
    int n  = blockIdx.x * 256 + threadIdx.x;
    int o0 = blockIdx.y * 8;
    int bt = blockIdx.z;
    const float* xp = X + (size_t)bt * 128 * 1024 + n;

    float acc[8] = {};
    for (int c = 0; c < 128; ++c) {
        float xv = xp[(size_t)c << 10];
        #pragma unroll
        for (int j = 0; j < 8; ++j) acc[j] += xv * W[(o0 + j) * 128 + c];
    }
    unsigned short* yp = Qbf + ((size_t)(bt * 1024) + n) * 128 + o0;
    #pragma unroll
    for (int j = 0; j < 8; ++j) yp[j] = f2bf(acc[j] * 0.1767766953f);
}

// K (bf16 n-major) + V^T (bf16 [bh][d][n]) in one pass.
__global__ __launch_bounds__(256) void proj_kv_kernel(
    const float* __restrict__ X, const float* __restrict__ Wk,
    const float* __restrict__ Wv, unsigned short* __restrict__ Kbf,
    unsigned short* __restrict__ VTbf)
{
    int n  = blockIdx.x * 256 + threadIdx.x;
    int o0 = blockIdx.y * 8;
    int bt = blockIdx.z;
    const float* xp = X + (size_t)bt * 192 * 1024 + n;

    float ak[8] = {}, av[8] = {};
    for (int c = 0; c < 192; ++c) {
        float xv = xp[(size_t)c << 10];
        #pragma unroll
        for (int j = 0; j < 8; ++j) {
            ak[j] += xv * Wk[(o0 + j) * 192 + c];
            av[j] += xv * Wv[(o0 + j) * 192 + c];
        }
    }
    unsigned short* kp = Kbf + ((size_t)(bt * 1024) + n) * 128 + o0;
    #pragma unroll
    for (int j = 0; j < 8; ++j) kp[j] = f2bf(ak[j]);
    const int h = o0 >> 5, d0 = o0 & 31;
    unsigned short* vp = VTbf + ((size_t)(bt * 4 + h) * 32 + d0) * 1024 + n;
    #pragma unroll
    for (int j = 0; j < 8; ++j) vp[(size_t)j << 10] = f2bf(av[j]);
}

// ---------------------------------------------------------------------------
// MFMA attention. Per wave: 16 queries, online softmax over 1024 keys in
// 32-key chunks. S^T = mfma(K_frag, Q_frag): lane q=l&15, keys 4g+r.
// P^T restaged via 1KB wave-private LDS -> B-frag; O^T = mfma(V^T, P^T).
// Block 256 thr = 4 waves = 64 q; grid (16 qblocks, 32 bh).
// ---------------------------------------------------------------------------
__global__ __launch_bounds__(256) void attn_mfma_kernel(
    const unsigned short* __restrict__ Qbf, const unsigned short* __restrict__ Kbf,
    const unsigned short* __restrict__ VTbf, float* __restrict__ attnT)
{
    __shared__ __align__(16) unsigned short P_lds[4][16][32];  // [wave][q][k]
    const int qb = blockIdx.x;
    const int bh = blockIdx.y;
    const int bt = bh >> 2, h = bh & 3;
    const int tid = threadIdx.x;
    const int wave = tid >> 6, lane = tid & 63;
    const int l15 = lane & 15, g = lane >> 4;
    const int q0 = qb * 64 + wave * 16;

    // Q B-frag: B[dim 8g+j][query l15]
    s16x8 qf = *(const s16x8*)(Qbf + ((size_t)(bt * 1024 + q0 + l15) * 128 + h * 32 + g * 8));

    f32x4 accO0 = (f32x4)0.f, accO1 = (f32x4)0.f;
    float m = -INFINITY, lsum = 0.f;

    const unsigned short* kbase = Kbf + (size_t)(bt * 1024) * 128 + h * 32 + g * 8;
    const unsigned short* vbase = VTbf + (size_t)bh * 32768 + (size_t)l15 * 1024 + g * 8;
    unsigned short* pl = &P_lds[wave][0][0];

    for (int kc = 0; kc < 1024; kc += 32) {
        // A-frags: K rows (16 keys each), V^T rows (d = l15, l15+16)
        s16x8 ak0 = *(const s16x8*)(kbase + (size_t)(kc + l15) * 128);
        s16x8 ak1 = *(const s16x8*)(kbase + (size_t)(kc + 16 + l15) * 128);
        s16x8 av0 = *(const s16x8*)(vbase + kc);
        s16x8 av1 = *(const s16x8*)(vbase + 16384 + kc);

        f32x4 s0 = __builtin_amdgcn_mfma_f32_16x16x32_bf16(ak0, qf, (f32x4)0.f, 0, 0, 0);
        f32x4 s1 = __builtin_amdgcn_mfma_f32_16x16x32_bf16(ak1, qf, (f32x4)0.f, 0, 0, 0);

        // per-query chunk max (cross the 4 lane-groups)
        float mx = fmaxf(fmaxf(fmaxf(s0[0], s0[1]), fmaxf(s0[2], s0[3])),
                         fmaxf(fmaxf(s1[0], s1[1]), fmaxf(s1[2], s1[3])));
        mx = fmaxf(mx, __shfl_xor(mx, 16));
        mx = fmaxf(mx, __shfl_xor(mx, 32));

        if (!__all(mx - m <= 8.f)) {        // defer-max (THR=8)
            float newm = fmaxf(m, mx);
            float f = __expf(m - newm);     // exp(-inf)=0 handles first chunk
            m = newm;
            lsum *= f;
            accO0 *= f; accO1 *= f;
        }

        float p[8];
        #pragma unroll
        for (int r = 0; r < 4; ++r) { p[r] = __expf(s0[r] - m); p[4 + r] = __expf(s1[r] - m); }
        lsum += ((p[0] + p[1]) + (p[2] + p[3])) + ((p[4] + p[5]) + (p[6] + p[7]));

        unsigned pk0 = (unsigned)f2bf(p[0]) | ((unsigned)f2bf(p[1]) << 16);
        unsigned pk1 = (unsigned)f2bf(p[2]) | ((unsigned)f2bf(p[3]) << 16);
        unsigned pk2 = (unsigned)f2bf(p[4]) | ((unsigned)f2bf(p[5]) << 16);
        unsigned pk3 = (unsigned)f2bf(p[6]) | ((unsigned)f2bf(p[7]) << 16);
        // write tile0 keys 4g..4g+3 at [q=l15][4g], tile1 at [q=l15][16+4g]
        *(uint2*)(pl + l15 * 32 + 4 * g)      = make_uint2(pk0, pk1);
        *(uint2*)(pl + l15 * 32 + 16 + 4 * g) = make_uint2(pk2, pk3);
        // B-frag for PV: [q=l15][8g .. 8g+7]
        s16x8 pb = *(const s16x8*)(pl + l15 * 32 + 8 * g);

        accO0 = __builtin_amdgcn_mfma_f32_16x16x32_bf16(av0, pb, accO0, 0, 0, 0);
        accO1 = __builtin_amdgcn_mfma_f32_16x16x32_bf16(av1, pb, accO1, 0, 0, 0);
    }

    float lt = lsum + __shfl_xor(lsum, 16);
    lt += __shfl_xor(lt, 32);
    float inv = 1.f / lt;

    float* outp = attnT + (size_t)bt * 131072 + (size_t)h * 32768 + q0 + l15;
    #pragma unroll
    for (int r = 0; r < 4; ++r) {
        int d = g * 4 + r;
        outp[(size_t)d << 10] = accO0[r] * inv;
        outp[(size_t)(d + 16) << 10] = accO1[r] * inv;
    }
}

// ---------------------------------------------------------------------------
// O projection (c-major f32 out, + bias).
// ---------------------------------------------------------------------------
__global__ __launch_bounds__(256) void proj_o_kernel(
    const float* __restrict__ X, const float* __restrict__ W,
    const float* __restrict__ bias, float* __restrict__ Y)
{
    int n  = blockIdx.x * 256 + threadIdx.x;
    int o0 = blockIdx.y * 8;
    int bt = blockIdx.z;
    const float* xp = X + (size_t)bt * 128 * 1024 + n;

    float acc[8] = {};
    for (int c = 0; c < 128; ++c) {
        float xv = xp[(size_t)c << 10];
        #pragma unroll
        for (int j = 0; j < 8; ++j) acc[j] += xv * W[(o0 + j) * 128 + c];
    }
    float* yp = Y + (size_t)bt * 131072 + n;
    #pragma unroll
    for (int j = 0; j < 8; ++j) yp[(size_t)(o0 + j) << 10] = acc[j] + bias[o0 + j];
}

// ---------------------------------------------------------------------------
extern "C" void kernel_launch(void* const* d_in, const int* in_sizes, int n_in,
                              void* d_out, int out_size, void* d_ws, size_t ws_size,
                              hipStream_t stream)
{
    const float* bev   = (const float*)d_in[0];
    const float* hd    = (const float*)d_in[1];
    const float* ego   = (const float*)d_in[2];
    const float* front = (const float*)d_in[3];
    const float* w_bev = (const float*)d_in[4];
    const float* b_bev = (const float*)d_in[5];
    const float* w_hd  = (const float*)d_in[6];
    const float* b_hd  = (const float*)d_in[7];
    const float* wq    = (const float*)d_in[8];
    const float* wk    = (const float*)d_in[9];
    const float* wv    = (const float*)d_in[10];
    const float* wo    = (const float*)d_in[11];
    const float* bo    = (const float*)d_in[12];
    const float* w_out = (const float*)d_in[13];
    const float* b_out = (const float*)d_in[14];
    float* out = (float*)d_out;
    float* ws  = (float*)d_ws;

    float* ATb = ws + OFF_AT;
    float* FUb = ws + OFF_FU;
    float* BFb = ws + OFF_BF;
    float* KVb = ws + OFF_KV;
    unsigned short* Qbf  = (unsigned short*)(ws + OFF_QBF);
    unsigned short* Kbf  = (unsigned short*)(ws + OFF_KBF);
    unsigned short* VTbf = (unsigned short*)(ws + OFF_VTB);
    unsigned short* xT1 = (unsigned short*)(ws + OFF_XT1);
    unsigned short* xT2 = (unsigned short*)(ws + OFF_XT2);
    unsigned short* xT3 = (unsigned short*)(ws + OFF_XT3);
    unsigned short* Wb1 = (unsigned short*)(ws + OFF_WB1);
    unsigned short* Wb2 = (unsigned short*)(ws + OFF_WB2);
    unsigned short* Wb3 = (unsigned short*)(ws + OFF_WB3);
    float* E1 = ws + OFF_E1;
    float* E2 = ws + OFF_E2;
    float* E3 = ws + OFF_E3;

    // S0: zero xT1..xT3 (border pre-zero)
    hipMemsetAsync(ws + OFF_XT1, 0, (size_t)(OFF_WB1 - OFF_XT1) * 4, stream);

    // S1: prep
    wprep_kernel<<<1440, 256, 0, stream>>>(w_bev, w_hd, w_out, Wb1, Wb2, Wb3);
    eprep_kernel<<<108, 256, 0, stream>>>(ego, w_bev, b_bev, b_hd, w_out, b_out, E1, E2, E3);
    xtprep_kernel<128><<<512, 256, 0, stream>>>(bev, xT1);
    xtprep_kernel<64><<<256, 256, 0, stream>>>(hd, xT2);

    // S2: convs
    conv_mfma_kernel<128, 4><<<dim3(16, 8), 128, 0, stream>>>(xT1, Wb1, E1, BFb, 128 * 1024);
    conv_mfma_kernel<64, 2><<<dim3(16, 8), 128, 0, stream>>>(xT2, Wb2, E2, KVb, 192 * 1024);

    // S3: resize
    resize_front_kernel<<<2048, 256, 0, stream>>>(front, KVb);

    // S4: projections -> bf16 operand layouts
    proj_q_kernel<<<dim3(4, 16, 8), 256, 0, stream>>>(BFb, wq, Qbf);
    proj_kv_kernel<<<dim3(4, 16, 8), 256, 0, stream>>>(KVb, wk, wv, Kbf, VTbf);

    // S5: MFMA attention -> attnT (no key-split, no combine)
    attn_mfma_kernel<<<dim3(16, 32), 256, 0, stream>>>(Qbf, Kbf, VTbf, ATb);

    // S6: output projection
    proj_o_kernel<<<dim3(4, 16, 8), 256, 0, stream>>>(ATb, wo, bo, FUb);

    // S7: fused -> xT3, final conv
    xtprep_kernel<128><<<512, 256, 0, stream>>>(FUb, xT3);
    conv_mfma_kernel<128, 4><<<dim3(16, 8), 128, 0, stream>>>(xT3, Wb3, E3, out, 128 * 1024);
}

// Round 5
// 229.917 us; speedup vs baseline: 3.1328x; 1.2023x over previous
//
#include <hip/hip_runtime.h>
#include <math.h>

// ---------------------------------------------------------------------------
// BEVHDMapFusionNet round 5: full bf16/MFMA inner pipeline.
//   conv(bf16, n-major out) -> proj MFMA (n-major chain) -> attn MFMA
//   -> proj_o MFMA (writes xT3 directly) -> final conv (f32 out).
//
// Workspace (float offsets):
//   OFF_BFN 0        BFn bf16 [8][1024][128]  (bev_feat, n-major)
//   OFF_KVN 524288   KVn bf16 [8][1024][192]  (hd_feat 0:128 | front 128:192)
//   OFF_QBF 1310720  Qbf bf16 [8][1024][128]  (scaled)
//   OFF_KBF 1835008  Kbf bf16 [8][1024][128]
//   OFF_VTB 2359296  VTbf bf16 [32][32][1024] ([bh][d][n])
//   OFF_ATB 2883584  ATbf bf16 [8][1024][128] (attn out, n-major)
//   OFF_XT1 3407872  xT1 bf16 [8][34][34][128]
//   OFF_XT2 3999744  xT2 bf16 [8][34][34][64]
//   OFF_XT3 4295680  xT3 bf16 [8][34][34][128]
//   OFF_WB1 4887552  Wb1 bf16 [9][128][128]
//   OFF_WB2 4961280  Wb2 bf16 [9][128][64]
//   OFF_WB3 4998144  Wb3 bf16 [9][128][128]
//   OFF_WQP 5071872  Wqb bf16 [128][128] (x 1/sqrt(32))
//   OFF_WKP 5080064  Wkb bf16 [128][192]
//   OFF_WVP 5092352  Wvb bf16 [128][192]
//   OFF_WOP 5104640  Wob bf16 [128][128]
//   OFF_E1  5112832  E1 f32 [8][128][9]
//   OFF_E2  5122048  E2
//   OFF_E3  5131264  E3 -> 5140480 floats = 20.6 MB
// ---------------------------------------------------------------------------

#define OFF_BFN 0u
#define OFF_KVN 524288u
#define OFF_QBF 1310720u
#define OFF_KBF 1835008u
#define OFF_VTB 2359296u
#define OFF_ATB 2883584u
#define OFF_XT1 3407872u
#define OFF_XT2 3999744u
#define OFF_XT3 4295680u
#define OFF_WB1 4887552u
#define OFF_WB2 4961280u
#define OFF_WB3 4998144u
#define OFF_WQP 5071872u
#define OFF_WKP 5080064u
#define OFF_WVP 5092352u
#define OFF_WOP 5104640u
#define OFF_E1  5112832u
#define OFF_E2  5122048u
#define OFF_E3  5131264u

typedef short s16x8 __attribute__((ext_vector_type(8)));
typedef float f32x4 __attribute__((ext_vector_type(4)));

__device__ __forceinline__ unsigned short f2bf(float f) {
    unsigned u = __float_as_uint(f);
    unsigned r = (u + 0x7fffu + ((u >> 16) & 1u)) >> 16;   // RNE
    return (unsigned short)r;
}

__device__ __forceinline__ void gl_lds16(const void* g, void* l) {
    __builtin_amdgcn_global_load_lds(
        (const __attribute__((address_space(1))) unsigned int*)g,
        (__attribute__((address_space(3))) unsigned int*)l, 16, 0, 0);
}

// ---------------------------------------------------------------------------
// prep_w: pack conv weights [tap][oc][C], proj weights row-major bf16
// (wq scaled), and E tables. gid ranges; grid 1868*256 = 478208.
// ---------------------------------------------------------------------------
__global__ __launch_bounds__(256) void prep_w_kernel(
    const float* __restrict__ w_bev, const float* __restrict__ w_hd,
    const float* __restrict__ w_out,
    const float* __restrict__ wq, const float* __restrict__ wk,
    const float* __restrict__ wv, const float* __restrict__ wo,
    const float* __restrict__ ego, const float* __restrict__ b_bev,
    const float* __restrict__ b_hd, const float* __restrict__ b_out,
    unsigned short* __restrict__ Wb1, unsigned short* __restrict__ Wb2,
    unsigned short* __restrict__ Wb3, unsigned short* __restrict__ Wqb,
    unsigned short* __restrict__ Wkb, unsigned short* __restrict__ Wvb,
    unsigned short* __restrict__ Wob,
    float* __restrict__ E1, float* __restrict__ E2, float* __restrict__ E3)
{
    int gid = blockIdx.x * 256 + threadIdx.x;
    if (gid < 368640) {
        // conv weight pack: Wb[tap][oc][C]
        const float* w; unsigned short* dst; int C, Cin, idx;
        if (gid < 147456)      { w = w_bev; dst = Wb1; C = 128; Cin = 144; idx = gid; }
        else if (gid < 221184) { w = w_hd;  dst = Wb2; C = 64;  Cin = 64;  idx = gid - 147456; }
        else                   { w = w_out; dst = Wb3; C = 128; Cin = 144; idx = gid - 221184; }
        int tap = idx / (128 * C);
        int rem = idx - tap * 128 * C;
        int oc = rem / C, ic = rem - oc * C;
        dst[idx] = f2bf(w[((size_t)oc * Cin + ic) * 9 + tap]);
    } else if (gid < 385024) {
        int idx = gid - 368640;
        Wqb[idx] = f2bf(wq[idx] * 0.1767766953f);
    } else if (gid < 409600) {
        int idx = gid - 385024;
        Wkb[idx] = f2bf(wk[idx]);
    } else if (gid < 434176) {
        int idx = gid - 409600;
        Wvb[idx] = f2bf(wv[idx]);
    } else if (gid < 450560) {
        int idx = gid - 434176;
        Wob[idx] = f2bf(wo[idx]);
    } else {
        // E tables
        int rem0 = gid - 450560;          // 0 .. 27647
        int which = rem0 / 9216;
        int rem = rem0 - which * 9216;
        int bt = rem / 1152;
        int r2 = rem - bt * 1152;
        int oc = r2 / 9, cls = r2 - oc * 9;
        int rc = cls / 3, cc = cls - rc * 3;

        if (which == 1) { E2[rem] = b_hd[oc]; return; }
        const float* w = (which == 0) ? w_bev : w_out;
        const float* b = (which == 0) ? b_bev : b_out;
        float* E = (which == 0) ? E1 : E3;

        int kyLo = (rc == 0) ? 1 : 0, kyHi = (rc == 2) ? 1 : 2;
        int kxLo = (cc == 0) ? 1 : 0, kxHi = (cc == 2) ? 1 : 2;
        float s = b[oc];
        for (int j = 0; j < 16; ++j) {
            float ev = ego[bt * 16 + j];
            const float* wp = w + ((size_t)oc * 144 + 128 + j) * 9;
            float t = 0.f;
            for (int ky = kyLo; ky <= kyHi; ++ky)
                for (int kx = kxLo; kx <= kxHi; ++kx)
                    t += wp[ky * 3 + kx];
            s += ev * t;
        }
        E[rem] = s;
    }
}

// ---------------------------------------------------------------------------
// prep_x: bev->xT1, hd->xT2 (bf16, halo layout), front->KVn[128:192] (resize).
// grid 1024*256 = 262144.
// ---------------------------------------------------------------------------
__global__ __launch_bounds__(256) void prep_x_kernel(
    const float* __restrict__ bev, const float* __restrict__ hd,
    const float* __restrict__ front,
    unsigned short* __restrict__ xT1, unsigned short* __restrict__ xT2,
    unsigned short* __restrict__ KVn)
{
    int gid = blockIdx.x * 256 + threadIdx.x;
    if (gid < 131072) {
        // bev (C=128): thread = (bt, 8-ch chunk, pixel)
        int p = gid & 1023, ch = (gid >> 10) & 15, bt = gid >> 14;
        int py = p >> 5, px = p & 31;
        const float* sp = bev + (size_t)bt * 131072 + ((size_t)ch << 13) + p;
        s16x8 v;
        #pragma unroll
        for (int j = 0; j < 8; ++j) v[j] = (short)f2bf(sp[(size_t)j << 10]);
        *(s16x8*)(xT1 + ((size_t)(bt * 34 + py + 1) * 34 + px + 1) * 128 + ch * 8) = v;
    } else if (gid < 196608) {
        // hd (C=64)
        int t = gid - 131072;
        int p = t & 1023, ch = (t >> 10) & 7, bt = t >> 13;
        int py = p >> 5, px = p & 31;
        const float* sp = hd + (size_t)bt * 65536 + ((size_t)ch << 13) + p;
        s16x8 v;
        #pragma unroll
        for (int j = 0; j < 8; ++j) v[j] = (short)f2bf(sp[(size_t)j << 10]);
        *(s16x8*)(xT2 + ((size_t)(bt * 34 + py + 1) * 34 + px + 1) * 64 + ch * 8) = v;
    } else {
        // bilinear 2x resize front 16x16 -> 32x32, 8 channels per thread
        int t = gid - 196608;               // (bt*1024 + pix)*8 + oct
        int oct = t & 7;
        int pix = (t >> 3) & 1023;
        int bt = t >> 13;
        int oy = pix >> 5, ox = pix & 31;

        float sy = 0.5f * oy - 0.25f, sx = 0.5f * ox - 0.25f;
        int iy0 = (int)floorf(sy); float fy = sy - iy0;
        int ix0 = (int)floorf(sx); float fx = sx - ix0;
        int iy1 = iy0 + 1, ix1 = ix0 + 1;
        iy0 = max(iy0, 0); iy1 = min(iy1, 15);
        ix0 = max(ix0, 0); ix1 = min(ix1, 15);
        float w00 = (1.f - fy) * (1.f - fx), w01 = (1.f - fy) * fx;
        float w10 = fy * (1.f - fx), w11 = fy * fx;

        const float* fp = front + ((size_t)(bt * 64 + oct * 8)) * 256;
        s16x8 v;
        #pragma unroll
        for (int j = 0; j < 8; ++j) {
            const float* f1 = fp + j * 256;
            float val = w00 * f1[iy0 * 16 + ix0] + w01 * f1[iy0 * 16 + ix1]
                      + w10 * f1[iy1 * 16 + ix0] + w11 * f1[iy1 * 16 + ix1];
            v[j] = (short)f2bf(val);
        }
        *(s16x8*)(KVn + ((size_t)(bt * 1024) + pix) * 192 + 128 + oct * 8) = v;
    }
}

// ---------------------------------------------------------------------------
// MFMA conv. OUTMODE 0: f32 c-major [bt][128][1024] (final). OUTMODE 1: bf16
// n-major [bt][1024][COUT]. relu + E in epilogue. Block 128 thr; grid (16,8).
// ---------------------------------------------------------------------------
template <int C, int ROUNDS, int OUTMODE, int COUT>
__global__ __launch_bounds__(128) void conv_mfma_kernel(
    const unsigned short* __restrict__ xT, const unsigned short* __restrict__ Wb,
    const float* __restrict__ E, void* __restrict__ yv)
{
    __shared__ __align__(16) char ldsb[8704];
    const int pt = blockIdx.x;
    const int bt = blockIdx.y;
    const int tid = threadIdx.x;
    const int wave = tid >> 6, lane = tid & 63;
    const int l15 = lane & 15, g = lane >> 4;
    const int oc0 = wave * 64;

    f32x4 acc[4][4];
    #pragma unroll
    for (int a = 0; a < 4; ++a)
        #pragma unroll
        for (int b = 0; b < 4; ++b) acc[a][b] = (f32x4)0.f;

    const unsigned short* xbt = xT + (size_t)bt * 34 * 34 * C;

    for (int kb = 0; kb < ROUNDS; ++kb) {
        const int ic0 = kb * 32;
        __syncthreads();
        #pragma unroll
        for (int i = 0; i < 5; ++i) {
            int ci = i * 128 + tid;
            if (ci < 544) {
                int e = ci >> 2, s = ci & 3;
                int sw = (e + (e >> 2)) & 3;
                int cch = s ^ sw;
                int ty = e / 34, tx = e - ty * 34;
                const unsigned short* src =
                    xbt + ((size_t)(pt * 2 + ty) * 34 + tx) * C + ic0 + cch * 8;
                gl_lds16(src, &ldsb[(i * 128 + wave * 64) * 16]);
            }
        }
        __syncthreads();

        #pragma unroll
        for (int tap = 0; tap < 9; ++tap) {
            const int ky = tap / 3, kx = tap - ky * 3;
            s16x8 afrag[4], bfrag[4];
            #pragma unroll
            for (int fm = 0; fm < 4; ++fm) {
                const unsigned short* ap =
                    Wb + ((size_t)(tap * 128 + oc0 + fm * 16 + l15)) * C + ic0 + g * 8;
                afrag[fm] = *(const s16x8*)ap;
            }
            #pragma unroll
            for (int fn = 0; fn < 4; ++fn) {
                int e = ((fn >> 1) + ky) * 34 + ((fn & 1) * 16 + l15 + kx);
                int byte = e * 64 + ((g ^ ((e + (e >> 2)) & 3)) << 4);
                bfrag[fn] = *(const s16x8*)(ldsb + byte);
            }
            #pragma unroll
            for (int fm = 0; fm < 4; ++fm)
                #pragma unroll
                for (int fn = 0; fn < 4; ++fn)
                    acc[fm][fn] = __builtin_amdgcn_mfma_f32_16x16x32_bf16(
                        afrag[fm], bfrag[fn], acc[fm][fn], 0, 0, 0);
        }
    }

    #pragma unroll
    for (int fn = 0; fn < 4; ++fn) {
        int r = pt * 2 + (fn >> 1);
        int c = (fn & 1) * 16 + l15;
        int rc = (r == 0) ? 0 : ((r == 31) ? 2 : 1);
        int cc = (c == 0) ? 0 : ((c == 31) ? 2 : 1);
        if (OUTMODE == 0) {
            float* yf = (float*)yv;
            #pragma unroll
            for (int fm = 0; fm < 4; ++fm) {
                #pragma unroll
                for (int rr = 0; rr < 4; ++rr) {
                    int oc = oc0 + fm * 16 + g * 4 + rr;
                    float ev = E[(bt * 128 + oc) * 9 + rc * 3 + cc];
                    float v = acc[fm][fn][rr] + ev;
                    yf[(size_t)bt * 131072 + ((size_t)oc << 10) + r * 32 + c] = fmaxf(v, 0.f);
                }
            }
        } else {
            unsigned short* yb = (unsigned short*)yv;
            unsigned short* rowp = yb + ((size_t)(bt * 1024) + r * 32 + c) * COUT;
            #pragma unroll
            for (int fm = 0; fm < 4; ++fm) {
                ushort4 pk;
                #pragma unroll
                for (int rr = 0; rr < 4; ++rr) {
                    int oc = oc0 + fm * 16 + g * 4 + rr;
                    float ev = E[(bt * 128 + oc) * 9 + rc * 3 + cc];
                    float v = fmaxf(acc[fm][fn][rr] + ev, 0.f);
                    ((unsigned short*)&pk)[rr] = f2bf(v);
                }
                *(ushort4*)(rowp + oc0 + fm * 16 + g * 4) = pk;
            }
        }
    }
}

// ---------------------------------------------------------------------------
// MFMA projections. Orientation D[o][n] = W · X^T: A = W row-major bf16,
// B = X n-major bf16 (contiguous 16B row loads). D: col=n (l15), row=o (g*4+r).
// Block 256 thr = 4 waves; wave = 16 n x 128 o. grid (16, 8).
// ---------------------------------------------------------------------------
__global__ __launch_bounds__(256) void proj_q_mfma(
    const unsigned short* __restrict__ X, const unsigned short* __restrict__ Wb,
    unsigned short* __restrict__ Y)
{
    const int wave = threadIdx.x >> 6, lane = threadIdx.x & 63;
    const int l15 = lane & 15, g = lane >> 4;
    const int n0 = blockIdx.x * 64 + wave * 16;
    const int bt = blockIdx.y;

    const unsigned short* xp = X + ((size_t)(bt * 1024 + n0 + l15)) * 128 + g * 8;

    f32x4 acc[8];
    #pragma unroll
    for (int ot = 0; ot < 8; ++ot) acc[ot] = (f32x4)0.f;

    #pragma unroll
    for (int ks = 0; ks < 4; ++ks) {
        s16x8 bfr = *(const s16x8*)(xp + ks * 32);
        #pragma unroll
        for (int ot = 0; ot < 8; ++ot) {
            s16x8 afr = *(const s16x8*)(Wb + ((size_t)(ot * 16 + l15)) * 128 + ks * 32 + g * 8);
            acc[ot] = __builtin_amdgcn_mfma_f32_16x16x32_bf16(afr, bfr, acc[ot], 0, 0, 0);
        }
    }

    unsigned short* yp = Y + ((size_t)(bt * 1024 + n0 + l15)) * 128;
    #pragma unroll
    for (int ot = 0; ot < 8; ++ot) {
        ushort4 pk;
        pk.x = f2bf(acc[ot][0]); pk.y = f2bf(acc[ot][1]);
        pk.z = f2bf(acc[ot][2]); pk.w = f2bf(acc[ot][3]);
        *(ushort4*)(yp + ot * 16 + g * 4) = pk;
    }
}

// K (n-major) + V (transposed [bh][d][n]) from KVn (C=192).
__global__ __launch_bounds__(256) void proj_kv_mfma(
    const unsigned short* __restrict__ X, const unsigned short* __restrict__ Wkb,
    const unsigned short* __restrict__ Wvb, unsigned short* __restrict__ K,
    unsigned short* __restrict__ VT)
{
    const int wave = threadIdx.x >> 6, lane = threadIdx.x & 63;
    const int l15 = lane & 15, g = lane >> 4;
    const int n0 = blockIdx.x * 64 + wave * 16;
    const int bt = blockIdx.y;

    const unsigned short* xp = X + ((size_t)(bt * 1024 + n0 + l15)) * 192 + g * 8;

    f32x4 ak[8], av[8];
    #pragma unroll
    for (int ot = 0; ot < 8; ++ot) { ak[ot] = (f32x4)0.f; av[ot] = (f32x4)0.f; }

    #pragma unroll
    for (int ks = 0; ks < 6; ++ks) {
        s16x8 bfr = *(const s16x8*)(xp + ks * 32);
        #pragma unroll
        for (int ot = 0; ot < 8; ++ot) {
            s16x8 afk = *(const s16x8*)(Wkb + ((size_t)(ot * 16 + l15)) * 192 + ks * 32 + g * 8);
            ak[ot] = __builtin_amdgcn_mfma_f32_16x16x32_bf16(afk, bfr, ak[ot], 0, 0, 0);
            s16x8 afv = *(const s16x8*)(Wvb + ((size_t)(ot * 16 + l15)) * 192 + ks * 32 + g * 8);
            av[ot] = __builtin_amdgcn_mfma_f32_16x16x32_bf16(afv, bfr, av[ot], 0, 0, 0);
        }
    }

    const int n = n0 + l15;
    unsigned short* kp = K + ((size_t)(bt * 1024) + n) * 128;
    #pragma unroll
    for (int ot = 0; ot < 8; ++ot) {
        ushort4 pk;
        pk.x = f2bf(ak[ot][0]); pk.y = f2bf(ak[ot][1]);
        pk.z = f2bf(ak[ot][2]); pk.w = f2bf(ak[ot][3]);
        *(ushort4*)(kp + ot * 16 + g * 4) = pk;
        // V transposed: o = ot*16 + g*4 + r; h = o>>5; d = o&31
        int h = ot >> 1, d0 = (ot & 1) * 16 + g * 4;
        unsigned short* vp = VT + ((size_t)(bt * 4 + h) * 32 + d0) * 1024 + n;
        #pragma unroll
        for (int r = 0; r < 4; ++r) vp[(size_t)r << 10] = f2bf(av[ot][r]);
    }
}

// O-projection + bias -> xT3 bf16 halo layout (no relu).
__global__ __launch_bounds__(256) void proj_o_mfma(
    const unsigned short* __restrict__ X, const unsigned short* __restrict__ Wb,
    const float* __restrict__ bo, unsigned short* __restrict__ xT3)
{
    const int wave = threadIdx.x >> 6, lane = threadIdx.x & 63;
    const int l15 = lane & 15, g = lane >> 4;
    const int n0 = blockIdx.x * 64 + wave * 16;
    const int bt = blockIdx.y;

    const unsigned short* xp = X + ((size_t)(bt * 1024 + n0 + l15)) * 128 + g * 8;

    f32x4 acc[8];
    #pragma unroll
    for (int ot = 0; ot < 8; ++ot) acc[ot] = (f32x4)0.f;

    #pragma unroll
    for (int ks = 0; ks < 4; ++ks) {
        s16x8 bfr = *(const s16x8*)(xp + ks * 32);
        #pragma unroll
        for (int ot = 0; ot < 8; ++ot) {
            s16x8 afr = *(const s16x8*)(Wb + ((size_t)(ot * 16 + l15)) * 128 + ks * 32 + g * 8);
            acc[ot] = __builtin_amdgcn_mfma_f32_16x16x32_bf16(afr, bfr, acc[ot], 0, 0, 0);
        }
    }

    const int pix = n0 + l15;
    const int py = pix >> 5, px = pix & 31;
    unsigned short* yp = xT3 + ((size_t)(bt * 34 + py + 1) * 34 + px + 1) * 128;
    #pragma unroll
    for (int ot = 0; ot < 8; ++ot) {
        float4 b4 = *(const float4*)(bo + ot * 16 + g * 4);
        ushort4 pk;
        pk.x = f2bf(acc[ot][0] + b4.x); pk.y = f2bf(acc[ot][1] + b4.y);
        pk.z = f2bf(acc[ot][2] + b4.z); pk.w = f2bf(acc[ot][3] + b4.w);
        *(ushort4*)(yp + ot * 16 + g * 4) = pk;
    }
}

// ---------------------------------------------------------------------------
// MFMA attention (round 4 structure), output bf16 n-major.
// ---------------------------------------------------------------------------
__global__ __launch_bounds__(256) void attn_mfma_kernel(
    const unsigned short* __restrict__ Qbf, const unsigned short* __restrict__ Kbf,
    const unsigned short* __restrict__ VTbf, unsigned short* __restrict__ AT)
{
    __shared__ __align__(16) unsigned short P_lds[4][16][32];
    const int qb = blockIdx.x;
    const int bh = blockIdx.y;
    const int bt = bh >> 2, h = bh & 3;
    const int tid = threadIdx.x;
    const int wave = tid >> 6, lane = tid & 63;
    const int l15 = lane & 15, g = lane >> 4;
    const int q0 = qb * 64 + wave * 16;

    s16x8 qf = *(const s16x8*)(Qbf + ((size_t)(bt * 1024 + q0 + l15) * 128 + h * 32 + g * 8));

    f32x4 accO0 = (f32x4)0.f, accO1 = (f32x4)0.f;
    float m = -INFINITY, lsum = 0.f;

    const unsigned short* kbase = Kbf + (size_t)(bt * 1024) * 128 + h * 32 + g * 8;
    const unsigned short* vbase = VTbf + (size_t)bh * 32768 + (size_t)l15 * 1024 + g * 8;
    unsigned short* pl = &P_lds[wave][0][0];

    for (int kc = 0; kc < 1024; kc += 32) {
        s16x8 ak0 = *(const s16x8*)(kbase + (size_t)(kc + l15) * 128);
        s16x8 ak1 = *(const s16x8*)(kbase + (size_t)(kc + 16 + l15) * 128);
        s16x8 av0 = *(const s16x8*)(vbase + kc);
        s16x8 av1 = *(const s16x8*)(vbase + 16384 + kc);

        f32x4 s0 = __builtin_amdgcn_mfma_f32_16x16x32_bf16(ak0, qf, (f32x4)0.f, 0, 0, 0);
        f32x4 s1 = __builtin_amdgcn_mfma_f32_16x16x32_bf16(ak1, qf, (f32x4)0.f, 0, 0, 0);

        float mx = fmaxf(fmaxf(fmaxf(s0[0], s0[1]), fmaxf(s0[2], s0[3])),
                         fmaxf(fmaxf(s1[0], s1[1]), fmaxf(s1[2], s1[3])));
        mx = fmaxf(mx, __shfl_xor(mx, 16));
        mx = fmaxf(mx, __shfl_xor(mx, 32));

        if (!__all(mx - m <= 8.f)) {
            float newm = fmaxf(m, mx);
            float f = __expf(m - newm);
            m = newm;
            lsum *= f;
            accO0 *= f; accO1 *= f;
        }

        float p[8];
        #pragma unroll
        for (int r = 0; r < 4; ++r) { p[r] = __expf(s0[r] - m); p[4 + r] = __expf(s1[r] - m); }
        lsum += ((p[0] + p[1]) + (p[2] + p[3])) + ((p[4] + p[5]) + (p[6] + p[7]));

        unsigned pk0 = (unsigned)f2bf(p[0]) | ((unsigned)f2bf(p[1]) << 16);
        unsigned pk1 = (unsigned)f2bf(p[2]) | ((unsigned)f2bf(p[3]) << 16);
        unsigned pk2 = (unsigned)f2bf(p[4]) | ((unsigned)f2bf(p[5]) << 16);
        unsigned pk3 = (unsigned)f2bf(p[6]) | ((unsigned)f2bf(p[7]) << 16);
        *(uint2*)(pl + l15 * 32 + 4 * g)      = make_uint2(pk0, pk1);
        *(uint2*)(pl + l15 * 32 + 16 + 4 * g) = make_uint2(pk2, pk3);
        s16x8 pb = *(const s16x8*)(pl + l15 * 32 + 8 * g);

        accO0 = __builtin_amdgcn_mfma_f32_16x16x32_bf16(av0, pb, accO0, 0, 0, 0);
        accO1 = __builtin_amdgcn_mfma_f32_16x16x32_bf16(av1, pb, accO1, 0, 0, 0);
    }

    float lt = lsum + __shfl_xor(lsum, 16);
    lt += __shfl_xor(lt, 32);
    float inv = 1.f / lt;

    unsigned short* outp = AT + ((size_t)(bt * 1024) + q0 + l15) * 128 + h * 32;
    ushort4 pk0, pk1;
    pk0.x = f2bf(accO0[0] * inv); pk0.y = f2bf(accO0[1] * inv);
    pk0.z = f2bf(accO0[2] * inv); pk0.w = f2bf(accO0[3] * inv);
    pk1.x = f2bf(accO1[0] * inv); pk1.y = f2bf(accO1[1] * inv);
    pk1.z = f2bf(accO1[2] * inv); pk1.w = f2bf(accO1[3] * inv);
    *(ushort4*)(outp + g * 4) = pk0;
    *(ushort4*)(outp + 16 + g * 4) = pk1;
}

// ---------------------------------------------------------------------------
extern "C" void kernel_launch(void* const* d_in, const int* in_sizes, int n_in,
                              void* d_out, int out_size, void* d_ws, size_t ws_size,
                              hipStream_t stream)
{
    const float* bev   = (const float*)d_in[0];
    const float* hd    = (const float*)d_in[1];
    const float* ego   = (const float*)d_in[2];
    const float* front = (const float*)d_in[3];
    const float* w_bev = (const float*)d_in[4];
    const float* b_bev = (const float*)d_in[5];
    const float* w_hd  = (const float*)d_in[6];
    const float* b_hd  = (const float*)d_in[7];
    const float* wq    = (const float*)d_in[8];
    const float* wk    = (const float*)d_in[9];
    const float* wv    = (const float*)d_in[10];
    const float* wo    = (const float*)d_in[11];
    const float* bo    = (const float*)d_in[12];
    const float* w_out = (const float*)d_in[13];
    const float* b_out = (const float*)d_in[14];
    float* out = (float*)d_out;
    float* ws  = (float*)d_ws;

    unsigned short* BFn  = (unsigned short*)(ws + OFF_BFN);
    unsigned short* KVn  = (unsigned short*)(ws + OFF_KVN);
    unsigned short* Qbf  = (unsigned short*)(ws + OFF_QBF);
    unsigned short* Kbf  = (unsigned short*)(ws + OFF_KBF);
    unsigned short* VTbf = (unsigned short*)(ws + OFF_VTB);
    unsigned short* ATbf = (unsigned short*)(ws + OFF_ATB);
    unsigned short* xT1  = (unsigned short*)(ws + OFF_XT1);
    unsigned short* xT2  = (unsigned short*)(ws + OFF_XT2);
    unsigned short* xT3  = (unsigned short*)(ws + OFF_XT3);
    unsigned short* Wb1  = (unsigned short*)(ws + OFF_WB1);
    unsigned short* Wb2  = (unsigned short*)(ws + OFF_WB2);
    unsigned short* Wb3  = (unsigned short*)(ws + OFF_WB3);
    unsigned short* Wqb  = (unsigned short*)(ws + OFF_WQP);
    unsigned short* Wkb  = (unsigned short*)(ws + OFF_WKP);
    unsigned short* Wvb  = (unsigned short*)(ws + OFF_WVP);
    unsigned short* Wob  = (unsigned short*)(ws + OFF_WOP);
    float* E1 = ws + OFF_E1;
    float* E2 = ws + OFF_E2;
    float* E3 = ws + OFF_E3;

    // S0: zero xT1..xT3 (pre-zero SAME-padding borders)
    hipMemsetAsync(ws + OFF_XT1, 0, (size_t)(OFF_WB1 - OFF_XT1) * 4, stream);

    // S1: prep (weights+E | inputs+resize)
    prep_w_kernel<<<1868, 256, 0, stream>>>(w_bev, w_hd, w_out, wq, wk, wv, wo,
                                            ego, b_bev, b_hd, b_out,
                                            Wb1, Wb2, Wb3, Wqb, Wkb, Wvb, Wob,
                                            E1, E2, E3);
    prep_x_kernel<<<1024, 256, 0, stream>>>(bev, hd, front, xT1, xT2, KVn);

    // S2: convs -> bf16 n-major
    conv_mfma_kernel<128, 4, 1, 128><<<dim3(16, 8), 128, 0, stream>>>(xT1, Wb1, E1, BFn);
    conv_mfma_kernel<64, 2, 1, 192><<<dim3(16, 8), 128, 0, stream>>>(xT2, Wb2, E2, KVn);

    // S3: projections (MFMA)
    proj_q_mfma<<<dim3(16, 8), 256, 0, stream>>>(BFn, Wqb, Qbf);
    proj_kv_mfma<<<dim3(16, 8), 256, 0, stream>>>(KVn, Wkb, Wvb, Kbf, VTbf);

    // S4: attention
    attn_mfma_kernel<<<dim3(16, 32), 256, 0, stream>>>(Qbf, Kbf, VTbf, ATbf);

    // S5: O-projection -> xT3 directly
    proj_o_mfma<<<dim3(16, 8), 256, 0, stream>>>(ATbf, Wob, bo, xT3);

    // S6: final conv -> f32 out
    conv_mfma_kernel<128, 4, 0, 0><<<dim3(16, 8), 128, 0, stream>>>(xT3, Wb3, E3, (void*)out);
}